// Round 6
// baseline (442.729 us; speedup 1.0000x reference)
//
#include <hip/hip_runtime.h>
#include <hip/hip_bf16.h>
#include <math.h>

// Problem constants
constexpr int B_ = 8, C_ = 256, H_ = 64, W_ = 64;
constexpr int N_ = H_ * W_;          // 4096
constexpr int NH_ = 8;
constexpr int CM_ = 2048;
constexpr int M_ = B_ * N_;          // 32768
constexpr float EPS_ = 1e-5f;

typedef __bf16 bf16_t;
typedef bf16_t bf16x8 __attribute__((ext_vector_type(8)));
typedef float f32x4 __attribute__((ext_vector_type(4)));
typedef float f32x16 __attribute__((ext_vector_type(16)));
typedef unsigned int u32x4 __attribute__((ext_vector_type(4)));

__device__ inline bf16_t f2b(float f) {
    __hip_bfloat16 h = __float2bfloat16(f);
    return *reinterpret_cast<bf16_t*>(&h);
}
__device__ inline float b2f(bf16_t b) {
    unsigned short u = *reinterpret_cast<unsigned short*>(&b);
    unsigned int x = (unsigned int)u << 16;
    return *reinterpret_cast<float*>(&x);
}
__device__ inline unsigned pk2(float lo, float hi) {
    bf16_t l = f2b(lo), h = f2b(hi);
    unsigned short ls = *reinterpret_cast<unsigned short*>(&l);
    unsigned short hs = *reinterpret_cast<unsigned short*>(&h);
    return ((unsigned)hs << 16) | (unsigned)ls;
}
__device__ inline float gelu_ap(float y) {
    float u = y * (0.7978845608f + 0.0356774081f * y * y);
    float e = __expf(2.0f * u);
    return y - y * __builtin_amdgcn_rcpf(e + 1.0f);
}

#define GLOAD_LDS16(gptr, lptr)                                                     \
    __builtin_amdgcn_global_load_lds(                                               \
        (const __attribute__((address_space(1))) void*)(gptr),                      \
        (__attribute__((address_space(3))) void*)(lptr), 16, 0, 0)

// ---------------------------------------------------------------------------
// Transpose [B,C,N] -> [B,N,C] (bf16 out). MODE 0: f32 in; MODE 1: bf16 in.
template <int MODE>
__global__ void transpose_cast(const void* __restrict__ in_, bf16_t* __restrict__ outb) {
    __shared__ float tile[32][33];
    int b  = blockIdx.z;
    int n0 = blockIdx.x * 32;
    int c0 = blockIdx.y * 32;
    int tx = threadIdx.x, ty = threadIdx.y;
#pragma unroll
    for (int i = ty; i < 32; i += 8) {
        size_t off = (size_t)b * C_ * N_ + (size_t)(c0 + i) * N_ + n0 + tx;
        tile[i][tx] = (MODE == 0) ? ((const float*)in_)[off] : b2f(((const bf16_t*)in_)[off]);
    }
    __syncthreads();
#pragma unroll
    for (int i = ty; i < 32; i += 8) {
        size_t off = (size_t)b * N_ * C_ + (size_t)(n0 + i) * C_ + c0 + tx;
        outb[off] = f2b(tile[tx][i]);
    }
}

// ---------------------------------------------------------------------------
// Weight cast + transpose: W [K,N] f32 -> Wt [N,K] bf16
__global__ void wcastT(const float* __restrict__ W, bf16_t* __restrict__ Wt,
                       int K, int N) {
    __shared__ float tile[32][33];
    int k0 = blockIdx.y * 32, n0 = blockIdx.x * 32;
    int tx = threadIdx.x, ty = threadIdx.y;
#pragma unroll
    for (int i = ty; i < 32; i += 8)
        tile[i][tx] = W[(size_t)(k0 + i) * N + n0 + tx];
    __syncthreads();
#pragma unroll
    for (int i = ty; i < 32; i += 8)
        Wt[(size_t)(n0 + i) * K + k0 + tx] = f2b(tile[tx][i]);
}

// ---------------------------------------------------------------------------
// bf16 MFMA GEMM (16x16x32): C = A[M,K] @ Bt[N,K]^T + bias, fused epilogues.
// EPI 1: z=b2f(tres_b)+acc+bias; repbn1 -> Cb (bf16)
// EPI 4: acc+bias -> Cb (bf16)
template <int EPI>
__global__ __launch_bounds__(256)
void gemm_bf16(const bf16_t* __restrict__ A, const bf16_t* __restrict__ Bt,
               const float* __restrict__ bias,
               float* __restrict__ Cf, bf16_t* __restrict__ Cb,
               int M, int N, int K,
               const bf16_t* __restrict__ tres_b,
               const float* __restrict__ g, const float* __restrict__ bb,
               const float* __restrict__ mm, const float* __restrict__ vv,
               const float* __restrict__ alpha, int row_off) {
    __shared__ bf16x8 ldsv[2048];          // 32 KB
    char* lds = (char*)ldsv;

    int tid  = threadIdx.x;
    int lane = tid & 63;
    int w    = tid >> 6;
    int wm   = w >> 1, wn = w & 1;
    int brow = blockIdx.y * 128, bcol = blockIdx.x * 128;
    int rowl = lane & 15, kq = lane >> 4;

    f32x4 acc[4][4] = {};

    for (int k0 = 0; k0 < K; k0 += 64) {
#pragma unroll
        for (int j = 0; j < 4; ++j) {
            int jj = w * 4 + j;
            int msub = jj >> 1, kh = jj & 1;
            const bf16_t* ga = A + ((size_t)(brow + msub * 16 + rowl) * K + k0 + kh * 32 + kq * 8);
            GLOAD_LDS16(ga, lds + jj * 1024);
            const bf16_t* gb = Bt + ((size_t)(bcol + msub * 16 + rowl) * K + k0 + kh * 32 + kq * 8);
            GLOAD_LDS16(gb, lds + 16384 + jj * 1024);
        }
        __syncthreads();
#pragma unroll
        for (int ks = 0; ks < 2; ++ks) {
            bf16x8 af[4], bfr[4];
#pragma unroll
            for (int m = 0; m < 4; ++m) af[m] = ldsv[((wm * 4 + m) * 2 + ks) * 64 + lane];
#pragma unroll
            for (int n = 0; n < 4; ++n) bfr[n] = ldsv[1024 + ((wn * 4 + n) * 2 + ks) * 64 + lane];
#pragma unroll
            for (int m = 0; m < 4; ++m)
#pragma unroll
                for (int n = 0; n < 4; ++n)
                    acc[m][n] = __builtin_amdgcn_mfma_f32_16x16x32_bf16(af[m], bfr[n], acc[m][n], 0, 0, 0);
        }
        __syncthreads();
    }

    float alpha_v = (EPI == 1) ? alpha[0] : 0.f;
#pragma unroll
    for (int m = 0; m < 4; ++m) {
#pragma unroll
        for (int n = 0; n < 4; ++n) {
            int col = bcol + wn * 64 + n * 16 + (lane & 15);
            float bv = bias[col];
#pragma unroll
            for (int r = 0; r < 4; ++r) {
                int row = brow + wm * 64 + m * 16 + (lane >> 4) * 4 + r;
                float y = acc[m][n][r] + bv;
                if (EPI == 4) {
                    Cb[(size_t)row * N + col] = f2b(y);
                } else {  // EPI 1
                    float z = b2f(tres_b[(size_t)row * N + col]) + y;
                    float rr = (z - mm[col]) * rsqrtf(vv[col] + EPS_) * g[col] + bb[col] + alpha_v * z;
                    Cb[(size_t)row * N + col] = f2b(rr);
                }
            }
        }
    }
}

// ---------------------------------------------------------------------------
// Fused FFN v2: out = repbn2(t + gelu(t@W1+b1)@W2 + b2), transposed to [B,C,N].
// LDS-free, barrier-free (raw s_barrier only for L1 sync). 32x32x16 MFMA.
// Grid M/128 x 4 waves; each wave: 32 rows x all 256 cols, fully in registers.
// Hidden in 64 chunks of 32. GEMM1 operand-swapped (h^T in regs, bias at GELU);
// W1/W2 chunks single-buffered in regs, reloaded right after last use so the
// following compute phase (~400-600 cyc) covers L1/L2 latency.
__global__ __launch_bounds__(256, 1)
void ffn_fused(const bf16_t* __restrict__ Aact, const bf16_t* __restrict__ W1t,
               const bf16_t* __restrict__ W2t,
               const float* __restrict__ bfc1, const float* __restrict__ bfc2,
               const float* __restrict__ g, const float* __restrict__ bb,
               const float* __restrict__ mm, const float* __restrict__ vv,
               const float* __restrict__ alpha, float* __restrict__ out) {
    const int tid = threadIdx.x;
    const int lane = tid & 63;
    const int w = tid >> 6;
    const int l31 = lane & 31;
    const int h = lane >> 5;
    const int brow = blockIdx.x * 128;
    const int row = brow + 32 * w + l31;

    // ---- A fragments -> registers (wave's own 32-row m-block)
    const bf16_t* arow = Aact + (size_t)row * 256 + h * 8;
    bf16x8 areg[16];
#pragma unroll
    for (int kc = 0; kc < 16; ++kc)
        areg[kc] = *(const bf16x8*)(arow + kc * 16);

    // ---- W chunk 0 -> registers
    const bf16_t* w1b = W1t + (size_t)l31 * 256 + h * 8;     // + c*8192 + kc*16
    const bf16_t* w2b = W2t + (size_t)l31 * 2048 + h * 8;    // + cb*65536 + c*32 + ks*16
    bf16x8 w1r[16], w2r[16];
#pragma unroll
    for (int kc = 0; kc < 16; ++kc)
        w1r[kc] = *(const bf16x8*)(w1b + kc * 16);
#pragma unroll
    for (int f = 0; f < 16; ++f)
        w2r[f] = *(const bf16x8*)(w2b + (size_t)(f >> 1) * 65536 + (f & 1) * 16);

    f32x16 acc2[8];
#pragma unroll
    for (int cb = 0; cb < 8; ++cb) acc2[cb] = (f32x16)0.f;

    for (int c = 0; c < 64; ++c) {
        // fc1 bias for this chunk (issued early; used at GELU)
        f32x4 bb4[4];
#pragma unroll
        for (int t = 0; t < 4; ++t)
            bb4[t] = *(const f32x4*)(bfc1 + 32 * c + 8 * t + 4 * h);

        // ---- GEMM1 (swapped): 2 interleaved 8-deep chains
        f32x16 a1a = (f32x16)0.f, a1b = (f32x16)0.f;
#pragma unroll
        for (int kc = 0; kc < 8; ++kc) {
            a1a = __builtin_amdgcn_mfma_f32_32x32x16_bf16(w1r[2 * kc], areg[2 * kc], a1a, 0, 0, 0);
            a1b = __builtin_amdgcn_mfma_f32_32x32x16_bf16(w1r[2 * kc + 1], areg[2 * kc + 1], a1b, 0, 0, 0);
        }
        f32x16 acc1 = a1a + a1b;

        // ---- reload W1 for next chunk (w1r dead now; latency covered by GELU+GEMM2)
        if (c < 63) {
            const bf16_t* p = w1b + (size_t)(c + 1) * 8192;
#pragma unroll
            for (int kc = 0; kc < 16; ++kc)
                w1r[kc] = *(const bf16x8*)(p + kc * 16);
        }

        // ---- bias + GELU + pack + half-wave exchange -> GEMM2 A-frags
        unsigned words[8];
#pragma unroll
        for (int t = 0; t < 4; ++t)
#pragma unroll
            for (int s = 0; s < 2; ++s)
                words[t * 2 + s] = pk2(gelu_ap(acc1[4 * t + 2 * s] + bb4[t][2 * s]),
                                       gelu_ap(acc1[4 * t + 2 * s + 1] + bb4[t][2 * s + 1]));
        bf16x8 hf[2];
#pragma unroll
        for (int ks = 0; ks < 2; ++ks) {
            unsigned u0 = words[(2 * ks) * 2 + 0], u1 = words[(2 * ks) * 2 + 1];
            unsigned v0 = words[(2 * ks + 1) * 2 + 0], v1 = words[(2 * ks + 1) * 2 + 1];
            unsigned su0 = __shfl_xor(u0, 32);
            unsigned su1 = __shfl_xor(u1, 32);
            unsigned sv0 = __shfl_xor(v0, 32);
            unsigned sv1 = __shfl_xor(v1, 32);
            u32x4 t4;
            t4[0] = h ? sv0 : u0;
            t4[1] = h ? sv1 : u1;
            t4[2] = h ? v0 : su0;
            t4[3] = h ? v1 : su1;
            hf[ks] = __builtin_bit_cast(bf16x8, t4);
        }

        // ---- GEMM2: 8 independent accumulators
#pragma unroll
        for (int cb = 0; cb < 8; ++cb) {
            acc2[cb] = __builtin_amdgcn_mfma_f32_32x32x16_bf16(hf[0], w2r[2 * cb], acc2[cb], 0, 0, 0);
            acc2[cb] = __builtin_amdgcn_mfma_f32_32x32x16_bf16(hf[1], w2r[2 * cb + 1], acc2[cb], 0, 0, 0);
        }

        // ---- reload W2 for next chunk (latency covered by next GEMM1+GELU)
        if (c < 63) {
            const bf16_t* p = w2b + (size_t)(c + 1) * 32;
#pragma unroll
            for (int f = 0; f < 16; ++f)
                w2r[f] = *(const bf16x8*)(p + (size_t)(f >> 1) * 65536 + (f & 1) * 16);
        }

        // keep the 4 waves loosely in step for L1 W-chunk reuse (no mem drain)
        __builtin_amdgcn_s_barrier();
    }

    // ---- epilogue: repbn2 + transpose to [B,C,N] (f32 out, float4 stores)
    float alpha_v = alpha[0];
#pragma unroll
    for (int cb = 0; cb < 8; ++cb) {
        int cc = cb * 32 + l31;
        float bv = bfc2[cc];
        float rs = rsqrtf(vv[cc] + EPS_) * g[cc];
        float bbv = bb[cc], mv = mm[cc];
#pragma unroll
        for (int q = 0; q < 4; ++q) {
            int mbase = brow + 32 * w + 8 * q + 4 * h;
            f32x4 o4;
#pragma unroll
            for (int j = 0; j < 4; ++j) {
                float z = b2f(Aact[(size_t)(mbase + j) * 256 + cc]) + acc2[cb][4 * q + j] + bv;
                o4[j] = (z - mv) * rs + bbv + alpha_v * z;
            }
            int bi = mbase >> 12, ni = mbase & (N_ - 1);
            *(f32x4*)(out + ((size_t)bi * C_ + cc) * N_ + ni) = o4;
        }
    }
}

// ---------------------------------------------------------------------------
// ctx partials: ctxp[seg][b*NH+h][d][e] = sum_{n in seg} relu(k[n,d]) * v[n,e]
__global__ void ctx_partial(const bf16_t* __restrict__ qkv, float* __restrict__ ctxp) {
    __shared__ float kb[64][40];
    __shared__ float vb[64][40];
    int seg = blockIdx.x;
    int bh  = blockIdx.y;
    int b = bh >> 3, h = bh & 7;
    int tid = threadIdx.x;
    int d  = tid >> 3;
    int e0 = (tid & 7) * 4;
    int lrow = tid >> 2, lcol = (tid & 3) * 8;
    float acc[4] = {0.f, 0.f, 0.f, 0.f};
    const size_t base = (size_t)b * N_ * 768 + h * 32;
    for (int n0 = seg * 512; n0 < seg * 512 + 512; n0 += 64) {
        size_t ra = base + (size_t)(n0 + lrow) * 768 + lcol;
        bf16x8 kv8 = *(const bf16x8*)(qkv + ra + 256);
        bf16x8 vv8 = *(const bf16x8*)(qkv + ra + 512);
#pragma unroll
        for (int j = 0; j < 8; ++j) {
            kb[lrow][lcol + j] = b2f(kv8[j]);
            vb[lrow][lcol + j] = b2f(vv8[j]);
        }
        __syncthreads();
#pragma unroll
        for (int nl = 0; nl < 64; ++nl) {
            float kv = fmaxf(kb[nl][d], 0.f);
#pragma unroll
            for (int j = 0; j < 4; ++j)
                acc[j] = fmaf(kv, vb[nl][e0 + j], acc[j]);
        }
        __syncthreads();
    }
    float* o = ctxp + ((size_t)seg * 64 + bh) * 1024 + d * 32 + e0;
#pragma unroll
    for (int j = 0; j < 4; ++j) o[j] = acc[j];
}

__global__ void ctx_reduce(const float* __restrict__ ctxp, float* __restrict__ ctx) {
    int idx = blockIdx.x * 256 + threadIdx.x;
    float s = 0.f;
#pragma unroll
    for (int seg = 0; seg < 8; ++seg) s += ctxp[(size_t)seg * 65536 + idx];
    ctx[idx] = s;
}

// ---------------------------------------------------------------------------
__global__ void attn_out(const bf16_t* __restrict__ qkv, const float* __restrict__ ctx,
                         bf16_t* __restrict__ img) {
    __shared__ float qb[64][33];
    __shared__ float cs[32][32];
    int n0 = blockIdx.x * 64;
    int bh = blockIdx.y;
    int b = bh >> 3, h = bh & 7;
    int tid = threadIdx.x;
    const float scale = 0.17677669529663687f;
    {
        float4 vv = ((const float4*)(ctx + (size_t)bh * 1024))[tid];
        ((float4*)&cs[0][0])[tid] = vv;
    }
    const size_t base = (size_t)b * N_ * 768 + h * 32;
    int lrow = tid >> 2, lcol = (tid & 3) * 8;
    {
        bf16x8 q8 = *(const bf16x8*)(qkv + base + (size_t)(n0 + lrow) * 768 + lcol);
#pragma unroll
        for (int j = 0; j < 8; ++j)
            qb[lrow][lcol + j] = fmaxf(b2f(q8[j]), 0.f) * scale;
    }
    __syncthreads();
    int nl = tid & 63, ebase = tid >> 6;
    bf16_t* outp = img + ((size_t)b * C_ + h * 32) * N_ + n0 + nl;
#pragma unroll
    for (int p = 0; p < 8; ++p) {
        int e = ebase + p * 4;
        float s = 0.f;
#pragma unroll
        for (int dd = 0; dd < 32; ++dd)
            s = fmaf(qb[nl][dd], cs[dd][e], s);
        outp[(size_t)e * N_] = f2b(s);
    }
}

// ---------------------------------------------------------------------------
__global__ __launch_bounds__(256)
void dwconv3x3(const bf16_t* __restrict__ img, const float* __restrict__ w,
               const float* __restrict__ bias, bf16_t* __restrict__ out) {
    __shared__ float sp[64][65];
    int bc = blockIdx.x;
    int c  = bc & 255;
    int tid = threadIdx.x;
    const bf16_t* ip = img + (size_t)bc * N_;
#pragma unroll
    for (int l = 0; l < 2; ++l) {
        int flat = (tid + l * 256) * 8;
        int row = flat >> 6, col = flat & 63;
        bf16x8 v8 = *(const bf16x8*)(ip + flat);
#pragma unroll
        for (int j = 0; j < 8; ++j) sp[row][col + j] = b2f(v8[j]);
    }
    float wv[9];
#pragma unroll
    for (int j = 0; j < 9; ++j) wv[j] = w[c * 9 + j];
    float bv = bias[c];
    __syncthreads();

    int y = tid >> 2, x0 = (tid & 3) * 16;
    float o[16];
#pragma unroll
    for (int i = 0; i < 16; ++i) o[i] = bv;
#pragma unroll
    for (int dy = -1; dy <= 1; ++dy) {
        int yy = y + dy;
        if (yy < 0 || yy > 63) continue;
#pragma unroll
        for (int dx = -1; dx <= 1; ++dx) {
            float wgt = wv[(dy + 1) * 3 + dx + 1];
#pragma unroll
            for (int i = 0; i < 16; ++i) {
                int xx = x0 + i + dx;
                float val = (xx < 0 || xx > 63) ? 0.f : sp[yy][xx];
                o[i] = fmaf(wgt, val, o[i]);
            }
        }
    }
    bf16_t ob[16];
#pragma unroll
    for (int i = 0; i < 16; ++i) ob[i] = f2b(o[i]);
    *(bf16x8*)(out + (size_t)bc * N_ + y * 64 + x0)     = *(bf16x8*)&ob[0];
    *(bf16x8*)(out + (size_t)bc * N_ + y * 64 + x0 + 8) = *(bf16x8*)&ob[8];
}

// ---------------------------------------------------------------------------
extern "C" void kernel_launch(void* const* d_in, const int* in_sizes, int n_in,
                              void* d_out, int out_size, void* d_ws, size_t ws_size,
                              hipStream_t stream) {
    const float* x     = (const float*)d_in[0];
    const float* Wqkv  = (const float*)d_in[1];
    const float* bqkv  = (const float*)d_in[2];
    const float* dw_w  = (const float*)d_in[3];
    const float* dw_b  = (const float*)d_in[4];
    const float* Wproj = (const float*)d_in[5];
    const float* bproj = (const float*)d_in[6];
    const float* bn1_g = (const float*)d_in[7];
    const float* bn1_b = (const float*)d_in[8];
    const float* bn1_m = (const float*)d_in[9];
    const float* bn1_v = (const float*)d_in[10];
    const float* alpha1= (const float*)d_in[11];
    const float* Wfc1  = (const float*)d_in[12];
    const float* bfc1  = (const float*)d_in[13];
    const float* Wfc2  = (const float*)d_in[14];
    const float* bfc2  = (const float*)d_in[15];
    const float* bn2_g = (const float*)d_in[16];
    const float* bn2_b = (const float*)d_in[17];
    const float* bn2_m = (const float*)d_in[18];
    const float* bn2_v = (const float*)d_in[19];
    const float* alpha2= (const float*)d_in[20];
    float* out = (float*)d_out;

    char* ws = (char*)d_ws;
    // Workspace layout (bytes), peak ~139 MB <= proven 170 MB:
    bf16_t* t_b2    = (bf16_t*)(ws);
    bf16_t* WqkvT   = (bf16_t*)(ws + 16777216);
    bf16_t* WprojT  = (bf16_t*)(ws + 17170432);
    bf16_t* Wfc1T   = (bf16_t*)(ws + 17301504);
    bf16_t* Wfc2T   = (bf16_t*)(ws + 18350080);
    float*  ctxp    = (float*)(ws + 19398656);
    float*  ctx     = (float*)(ws + 21495808);
    bf16_t* t_b     = (bf16_t*)(ws + 21757952);
    bf16_t* qkv_b   = (bf16_t*)(ws + 38535168);
    bf16_t* img_b   = (bf16_t*)(ws + 88866816);
    bf16_t* conv_b  = (bf16_t*)(ws + 105644032);
    bf16_t* convT_b = (bf16_t*)(ws + 122421248);

    // ph1: x -> t_b (bf16); weight casts
    transpose_cast<0><<<dim3(N_ / 32, C_ / 32, B_), dim3(32, 8), 0, stream>>>(x, t_b);
    wcastT<<<dim3(768 / 32, C_ / 32), dim3(32, 8), 0, stream>>>(Wqkv, WqkvT, C_, 768);
    wcastT<<<dim3(C_ / 32, C_ / 32), dim3(32, 8), 0, stream>>>(Wproj, WprojT, C_, C_);
    wcastT<<<dim3(CM_ / 32, C_ / 32), dim3(32, 8), 0, stream>>>(Wfc1, Wfc1T, C_, CM_);
    wcastT<<<dim3(C_ / 32, CM_ / 32), dim3(32, 8), 0, stream>>>(Wfc2, Wfc2T, CM_, C_);

    // ph2: qkv_b = bf16(t @ Wqkv + bqkv)
    gemm_bf16<4><<<dim3(768 / 128, M_ / 128), 256, 0, stream>>>(
        t_b, WqkvT, bqkv, nullptr, qkv_b, M_, 768, C_,
        nullptr, nullptr, nullptr, nullptr, nullptr, nullptr, 0);

    // ph3: ctx = relu(k)^T v
    ctx_partial<<<dim3(8, B_ * NH_), 256, 0, stream>>>(qkv_b, ctxp);
    ctx_reduce<<<256, 256, 0, stream>>>(ctxp, ctx);

    // ph4: img_b = (relu(q)*scale) @ ctx   [B,C,N] bf16
    attn_out<<<dim3(N_ / 64, B_ * NH_), 256, 0, stream>>>(qkv_b, ctx, img_b);

    // ph5: depthwise conv (bf16 -> bf16)
    dwconv3x3<<<B_ * C_, 256, 0, stream>>>(img_b, dw_w, dw_b, conv_b);

    // ph6: conv_b -> convT_b (bf16 [B,N,C])
    transpose_cast<1><<<dim3(N_ / 32, C_ / 32, B_), dim3(32, 8), 0, stream>>>(conv_b, convT_b);

    // ph7: t_b2 = repbn1(t_b + convT @ Wproj + bproj)   (bf16)
    gemm_bf16<1><<<dim3(C_ / 128, M_ / 128), 256, 0, stream>>>(
        convT_b, WprojT, bproj, nullptr, t_b2, M_, C_, C_,
        t_b, bn1_g, bn1_b, bn1_m, bn1_v, alpha1, 0);

    // ph8: fused FFN v2 (LDS-free, reg-resident)
    ffn_fused<<<M_ / 128, 256, 0, stream>>>(
        t_b2, Wfc1T, Wfc2T, bfc1, bfc2,
        bn2_g, bn2_b, bn2_m, bn2_v, alpha2, out);
}

// Round 7
// 342.524 us; speedup vs baseline: 1.2925x; 1.2925x over previous
//
#include <hip/hip_runtime.h>
#include <hip/hip_bf16.h>
#include <math.h>

// Problem constants
constexpr int B_ = 8, C_ = 256, H_ = 64, W_ = 64;
constexpr int N_ = H_ * W_;          // 4096
constexpr int NH_ = 8;
constexpr int CM_ = 2048;
constexpr int M_ = B_ * N_;          // 32768
constexpr float EPS_ = 1e-5f;

typedef __bf16 bf16_t;
typedef bf16_t bf16x8 __attribute__((ext_vector_type(8)));
typedef float f32x4 __attribute__((ext_vector_type(4)));

__device__ inline bf16_t f2b(float f) {
    __hip_bfloat16 h = __float2bfloat16(f);
    return *reinterpret_cast<bf16_t*>(&h);
}
__device__ inline float b2f(bf16_t b) {
    unsigned short u = *reinterpret_cast<unsigned short*>(&b);
    unsigned int x = (unsigned int)u << 16;
    return *reinterpret_cast<float*>(&x);
}
__device__ inline float gelu_ap(float y) {
    float u = y * (0.7978845608f + 0.0356774081f * y * y);
    float e = __expf(2.0f * u);
    return y - y * __builtin_amdgcn_rcpf(e + 1.0f);
}

#define GLOAD_LDS16(gptr, lptr)                                                     \
    __builtin_amdgcn_global_load_lds(                                               \
        (const __attribute__((address_space(1))) void*)(gptr),                      \
        (__attribute__((address_space(3))) void*)(lptr), 16, 0, 0)

// ---------------------------------------------------------------------------
// Transpose [B,C,N] -> [B,N,C] (bf16 out). MODE 0: f32 in; MODE 1: bf16 in.
template <int MODE>
__global__ void transpose_cast(const void* __restrict__ in_, bf16_t* __restrict__ outb) {
    __shared__ float tile[32][33];
    int b  = blockIdx.z;
    int n0 = blockIdx.x * 32;
    int c0 = blockIdx.y * 32;
    int tx = threadIdx.x, ty = threadIdx.y;
#pragma unroll
    for (int i = ty; i < 32; i += 8) {
        size_t off = (size_t)b * C_ * N_ + (size_t)(c0 + i) * N_ + n0 + tx;
        tile[i][tx] = (MODE == 0) ? ((const float*)in_)[off] : b2f(((const bf16_t*)in_)[off]);
    }
    __syncthreads();
#pragma unroll
    for (int i = ty; i < 32; i += 8) {
        size_t off = (size_t)b * N_ * C_ + (size_t)(n0 + i) * C_ + c0 + tx;
        outb[off] = f2b(tile[tx][i]);
    }
}

// ---------------------------------------------------------------------------
// Weight cast + transpose: W [K,N] f32 -> Wt [N,K] bf16
__global__ void wcastT(const float* __restrict__ W, bf16_t* __restrict__ Wt,
                       int K, int N) {
    __shared__ float tile[32][33];
    int k0 = blockIdx.y * 32, n0 = blockIdx.x * 32;
    int tx = threadIdx.x, ty = threadIdx.y;
#pragma unroll
    for (int i = ty; i < 32; i += 8)
        tile[i][tx] = W[(size_t)(k0 + i) * N + n0 + tx];
    __syncthreads();
#pragma unroll
    for (int i = ty; i < 32; i += 8)
        Wt[(size_t)(n0 + i) * K + k0 + tx] = f2b(tile[tx][i]);
}

// ---------------------------------------------------------------------------
// bf16 MFMA GEMM (16x16x32): C = A[M,K] @ Bt[N,K]^T + bias, fused epilogues.
// 128x128 tile, BK=64, 4 waves. XCD-aware bijective block swizzle.
// Epilogues (vectorized stores):
//  EPI 1: z=b2f(tres)+acc+bias; repbn1 -> Cb bf16 row-major  (LDS-staged bf16x8)
//  EPI 2: gelu(acc+bias) -> Cb bf16 row-major                (LDS-staged bf16x8)
//  EPI 4: acc+bias -> Cb bf16 row-major                      (LDS-staged bf16x8)
//  EPI 3: z=b2f(tres)+acc+bias; repbn2 -> Cf f32 [B,C,N]     (native f32x4: the
//         frag's 4 r-rows are consecutive ni in the transposed output)
template <int EPI>
__global__ __launch_bounds__(256)
void gemm_bf16(const bf16_t* __restrict__ A, const bf16_t* __restrict__ Bt,
               const float* __restrict__ bias,
               float* __restrict__ Cf, bf16_t* __restrict__ Cb,
               int M, int N, int K,
               const bf16_t* __restrict__ tres_b,
               const float* __restrict__ g, const float* __restrict__ bb,
               const float* __restrict__ mm, const float* __restrict__ vv,
               const float* __restrict__ alpha) {
    __shared__ bf16x8 ldsv[2048];          // 32 KB
    char* lds = (char*)ldsv;

    int tid  = threadIdx.x;
    int lane = tid & 63;
    int w    = tid >> 6;
    int wm   = w >> 1, wn = w & 1;

    // XCD-aware bijective swizzle: consecutive same-XCD blocks share a row-panel.
    int nwg = gridDim.x * gridDim.y;
    int bid = blockIdx.y * gridDim.x + blockIdx.x;
    int swz = (bid & 7) * (nwg >> 3) + (bid >> 3);
    int bx = swz % gridDim.x, by = swz / gridDim.x;
    int brow = by * 128, bcol = bx * 128;

    int rowl = lane & 15, kq = lane >> 4;

    f32x4 acc[4][4] = {};

    for (int k0 = 0; k0 < K; k0 += 64) {
#pragma unroll
        for (int j = 0; j < 4; ++j) {
            int jj = w * 4 + j;
            int msub = jj >> 1, kh = jj & 1;
            const bf16_t* ga = A + ((size_t)(brow + msub * 16 + rowl) * K + k0 + kh * 32 + kq * 8);
            GLOAD_LDS16(ga, lds + jj * 1024);
            const bf16_t* gb = Bt + ((size_t)(bcol + msub * 16 + rowl) * K + k0 + kh * 32 + kq * 8);
            GLOAD_LDS16(gb, lds + 16384 + jj * 1024);
        }
        __syncthreads();
#pragma unroll
        for (int ks = 0; ks < 2; ++ks) {
            bf16x8 af[4], bfr[4];
#pragma unroll
            for (int m = 0; m < 4; ++m) af[m] = ldsv[((wm * 4 + m) * 2 + ks) * 64 + lane];
#pragma unroll
            for (int n = 0; n < 4; ++n) bfr[n] = ldsv[1024 + ((wn * 4 + n) * 2 + ks) * 64 + lane];
#pragma unroll
            for (int m = 0; m < 4; ++m)
#pragma unroll
                for (int n = 0; n < 4; ++n)
                    acc[m][n] = __builtin_amdgcn_mfma_f32_16x16x32_bf16(af[m], bfr[n], acc[m][n], 0, 0, 0);
        }
        __syncthreads();   // last iter: all waves done with frag LDS -> safe to reuse
    }

    float alpha_v = (EPI == 1 || EPI == 3) ? alpha[0] : 0.f;

    if (EPI == 3) {
        // native f32x4 stores into [B,C,N]
#pragma unroll
        for (int m = 0; m < 4; ++m) {
            int mbase = brow + wm * 64 + m * 16 + (lane >> 4) * 4;
            int bi = mbase >> 12, ni = mbase & (N_ - 1);
#pragma unroll
            for (int n = 0; n < 4; ++n) {
                int col = bcol + wn * 64 + n * 16 + (lane & 15);
                float bv = bias[col];
                float rs = rsqrtf(vv[col] + EPS_) * g[col];
                float bbv = bb[col], mv = mm[col];
                f32x4 o4;
#pragma unroll
                for (int r = 0; r < 4; ++r) {
                    float z = b2f(tres_b[(size_t)(mbase + r) * C_ + col]) + acc[m][n][r] + bv;
                    o4[r] = (z - mv) * rs + bbv + alpha_v * z;
                }
                *(f32x4*)(Cf + ((size_t)bi * C_ + col) * N_ + ni) = o4;
            }
        }
    } else {
        // LDS-staged transpose epilogue -> bf16x8 row-major stores
        float* fl = (float*)ldsv + w * 2048;   // 8 KB per wave: 32 rows x 64 cols
        const int c8 = lane & 7, rbase = (lane >> 3) * 4;
#pragma unroll
        for (int half = 0; half < 2; ++half) {
            if (half)
                asm volatile("s_waitcnt lgkmcnt(0)" ::: "memory");
#pragma unroll
            for (int m2 = 0; m2 < 2; ++m2) {
                int m = half * 2 + m2;
#pragma unroll
                for (int n = 0; n < 4; ++n)
#pragma unroll
                    for (int r = 0; r < 4; ++r) {
                        int rl = m2 * 16 + (lane >> 4) * 4 + r;
                        int cl = n * 16 + (lane & 15);
                        int scl = cl ^ (((rl >> 2) & 3) << 4);   // bank-balance
                        fl[rl * 64 + scl] = acc[m][n][r];
                    }
            }
            asm volatile("s_waitcnt lgkmcnt(0)" ::: "memory");
#pragma unroll
            for (int rr = 0; rr < 4; ++rr) {
                int rl = rbase + rr;
                int xr = ((rl >> 2) & 3) << 4;
                f32x4 lo = *(f32x4*)&fl[rl * 64 + ((c8 * 8) ^ xr)];
                f32x4 hi = *(f32x4*)&fl[rl * 64 + ((c8 * 8 + 4) ^ xr)];
                int grow = brow + wm * 64 + half * 32 + rl;
                int gcol = bcol + wn * 64 + c8 * 8;
                f32x4 b0 = *(const f32x4*)(bias + gcol);
                f32x4 b1 = *(const f32x4*)(bias + gcol + 4);
                float y[8];
#pragma unroll
                for (int j = 0; j < 4; ++j) { y[j] = lo[j] + b0[j]; y[4 + j] = hi[j] + b1[j]; }
                bf16_t ob[8];
                if (EPI == 4) {
#pragma unroll
                    for (int j = 0; j < 8; ++j) ob[j] = f2b(y[j]);
                } else if (EPI == 2) {
#pragma unroll
                    for (int j = 0; j < 8; ++j) ob[j] = f2b(gelu_ap(y[j]));
                } else {  // EPI 1
                    bf16x8 t8 = *(const bf16x8*)(tres_b + (size_t)grow * N + gcol);
                    f32x4 g0 = *(const f32x4*)(g + gcol),  g1 = *(const f32x4*)(g + gcol + 4);
                    f32x4 B0 = *(const f32x4*)(bb + gcol), B1 = *(const f32x4*)(bb + gcol + 4);
                    f32x4 m0 = *(const f32x4*)(mm + gcol), m1 = *(const f32x4*)(mm + gcol + 4);
                    f32x4 v0 = *(const f32x4*)(vv + gcol), v1 = *(const f32x4*)(vv + gcol + 4);
#pragma unroll
                    for (int j = 0; j < 8; ++j) {
                        float gv = j < 4 ? g0[j] : g1[j - 4];
                        float bbv = j < 4 ? B0[j] : B1[j - 4];
                        float mv = j < 4 ? m0[j] : m1[j - 4];
                        float vr = j < 4 ? v0[j] : v1[j - 4];
                        float z = b2f(t8[j]) + y[j];
                        float r2 = (z - mv) * rsqrtf(vr + EPS_) * gv + bbv + alpha_v * z;
                        ob[j] = f2b(r2);
                    }
                }
                *(bf16x8*)(Cb + (size_t)grow * N + gcol) = *(bf16x8*)ob;
            }
        }
    }
}

// ---------------------------------------------------------------------------
// ctx partials: ctxp[seg][b*NH+h][d][e] = sum_{n in seg} relu(k[n,d]) * v[n,e]
__global__ void ctx_partial(const bf16_t* __restrict__ qkv, float* __restrict__ ctxp) {
    __shared__ float kb[64][40];
    __shared__ float vb[64][40];
    int seg = blockIdx.x;
    int bh  = blockIdx.y;
    int b = bh >> 3, h = bh & 7;
    int tid = threadIdx.x;
    int d  = tid >> 3;
    int e0 = (tid & 7) * 4;
    int lrow = tid >> 2, lcol = (tid & 3) * 8;
    float acc[4] = {0.f, 0.f, 0.f, 0.f};
    const size_t base = (size_t)b * N_ * 768 + h * 32;
    for (int n0 = seg * 512; n0 < seg * 512 + 512; n0 += 64) {
        size_t ra = base + (size_t)(n0 + lrow) * 768 + lcol;
        bf16x8 kv8 = *(const bf16x8*)(qkv + ra + 256);
        bf16x8 vv8 = *(const bf16x8*)(qkv + ra + 512);
#pragma unroll
        for (int j = 0; j < 8; ++j) {
            kb[lrow][lcol + j] = b2f(kv8[j]);
            vb[lrow][lcol + j] = b2f(vv8[j]);
        }
        __syncthreads();
#pragma unroll
        for (int nl = 0; nl < 64; ++nl) {
            float kv = fmaxf(kb[nl][d], 0.f);
#pragma unroll
            for (int j = 0; j < 4; ++j)
                acc[j] = fmaf(kv, vb[nl][e0 + j], acc[j]);
        }
        __syncthreads();
    }
    float* o = ctxp + ((size_t)seg * 64 + bh) * 1024 + d * 32 + e0;
#pragma unroll
    for (int j = 0; j < 4; ++j) o[j] = acc[j];
}

__global__ void ctx_reduce(const float* __restrict__ ctxp, float* __restrict__ ctx) {
    int idx = blockIdx.x * 256 + threadIdx.x;
    float s = 0.f;
#pragma unroll
    for (int seg = 0; seg < 8; ++seg) s += ctxp[(size_t)seg * 65536 + idx];
    ctx[idx] = s;
}

// ---------------------------------------------------------------------------
__global__ void attn_out(const bf16_t* __restrict__ qkv, const float* __restrict__ ctx,
                         bf16_t* __restrict__ img) {
    __shared__ float qb[64][33];
    __shared__ float cs[32][32];
    int n0 = blockIdx.x * 64;
    int bh = blockIdx.y;
    int b = bh >> 3, h = bh & 7;
    int tid = threadIdx.x;
    const float scale = 0.17677669529663687f;
    {
        float4 vv = ((const float4*)(ctx + (size_t)bh * 1024))[tid];
        ((float4*)&cs[0][0])[tid] = vv;
    }
    const size_t base = (size_t)b * N_ * 768 + h * 32;
    int lrow = tid >> 2, lcol = (tid & 3) * 8;
    {
        bf16x8 q8 = *(const bf16x8*)(qkv + base + (size_t)(n0 + lrow) * 768 + lcol);
#pragma unroll
        for (int j = 0; j < 8; ++j)
            qb[lrow][lcol + j] = fmaxf(b2f(q8[j]), 0.f) * scale;
    }
    __syncthreads();
    int nl = tid & 63, ebase = tid >> 6;
    bf16_t* outp = img + ((size_t)b * C_ + h * 32) * N_ + n0 + nl;
#pragma unroll
    for (int p = 0; p < 8; ++p) {
        int e = ebase + p * 4;
        float s = 0.f;
#pragma unroll
        for (int dd = 0; dd < 32; ++dd)
            s = fmaf(qb[nl][dd], cs[dd][e], s);
        outp[(size_t)e * N_] = f2b(s);
    }
}

// ---------------------------------------------------------------------------
__global__ __launch_bounds__(256)
void dwconv3x3(const bf16_t* __restrict__ img, const float* __restrict__ w,
               const float* __restrict__ bias, bf16_t* __restrict__ out) {
    __shared__ float sp[64][65];
    int bc = blockIdx.x;
    int c  = bc & 255;
    int tid = threadIdx.x;
    const bf16_t* ip = img + (size_t)bc * N_;
#pragma unroll
    for (int l = 0; l < 2; ++l) {
        int flat = (tid + l * 256) * 8;
        int row = flat >> 6, col = flat & 63;
        bf16x8 v8 = *(const bf16x8*)(ip + flat);
#pragma unroll
        for (int j = 0; j < 8; ++j) sp[row][col + j] = b2f(v8[j]);
    }
    float wv[9];
#pragma unroll
    for (int j = 0; j < 9; ++j) wv[j] = w[c * 9 + j];
    float bv = bias[c];
    __syncthreads();

    int y = tid >> 2, x0 = (tid & 3) * 16;
    float o[16];
#pragma unroll
    for (int i = 0; i < 16; ++i) o[i] = bv;
#pragma unroll
    for (int dy = -1; dy <= 1; ++dy) {
        int yy = y + dy;
        if (yy < 0 || yy > 63) continue;
#pragma unroll
        for (int dx = -1; dx <= 1; ++dx) {
            float wgt = wv[(dy + 1) * 3 + dx + 1];
#pragma unroll
            for (int i = 0; i < 16; ++i) {
                int xx = x0 + i + dx;
                float val = (xx < 0 || xx > 63) ? 0.f : sp[yy][xx];
                o[i] = fmaf(wgt, val, o[i]);
            }
        }
    }
    bf16_t ob[16];
#pragma unroll
    for (int i = 0; i < 16; ++i) ob[i] = f2b(o[i]);
    *(bf16x8*)(out + (size_t)bc * N_ + y * 64 + x0)     = *(bf16x8*)&ob[0];
    *(bf16x8*)(out + (size_t)bc * N_ + y * 64 + x0 + 8) = *(bf16x8*)&ob[8];
}

// ---------------------------------------------------------------------------
extern "C" void kernel_launch(void* const* d_in, const int* in_sizes, int n_in,
                              void* d_out, int out_size, void* d_ws, size_t ws_size,
                              hipStream_t stream) {
    const float* x     = (const float*)d_in[0];
    const float* Wqkv  = (const float*)d_in[1];
    const float* bqkv  = (const float*)d_in[2];
    const float* dw_w  = (const float*)d_in[3];
    const float* dw_b  = (const float*)d_in[4];
    const float* Wproj = (const float*)d_in[5];
    const float* bproj = (const float*)d_in[6];
    const float* bn1_g = (const float*)d_in[7];
    const float* bn1_b = (const float*)d_in[8];
    const float* bn1_m = (const float*)d_in[9];
    const float* bn1_v = (const float*)d_in[10];
    const float* alpha1= (const float*)d_in[11];
    const float* Wfc1  = (const float*)d_in[12];
    const float* bfc1  = (const float*)d_in[13];
    const float* Wfc2  = (const float*)d_in[14];
    const float* bfc2  = (const float*)d_in[15];
    const float* bn2_g = (const float*)d_in[16];
    const float* bn2_b = (const float*)d_in[17];
    const float* bn2_m = (const float*)d_in[18];
    const float* bn2_v = (const float*)d_in[19];
    const float* alpha2= (const float*)d_in[20];
    float* out = (float*)d_out;

    char* ws = (char*)d_ws;
    // Workspace layout (bytes), peak 155,975,680 <= proven 170,131,456:
    //   t_b2    @ 0            16,777,216  bf16 [B,N,C]      (ph7..ph9)
    //   WqkvT   @ 16,777,216      393,216
    //   WprojT  @ 17,170,432      131,072
    //   Wfc1T   @ 17,301,504    1,048,576
    //   Wfc2T   @ 18,350,080    1,048,576
    //   ctxp    @ 19,398,656    2,097,152  (ph3)
    //   ctx     @ 21,495,808      262,144  (ph3..ph4)
    //   t_b     @ 21,757,952   16,777,216  bf16 [B,N,C]      (ph1..ph7)
    //   qkv_b   @ 38,535,168   50,331,648  bf16 [B,N,768]    (ph2..ph4)
    //   img_b   @ 88,866,816   16,777,216  bf16 [B,C,N]      (ph4..ph5)
    //   conv_b  @ 105,644,032  16,777,216  bf16 [B,C,N]      (ph5..ph6)
    //   convT_b @ 122,421,248  16,777,216  bf16 [B,N,C]      (ph6..ph7)
    //   hidden  @ 21,757,952  134,217,728  bf16 [M,CM]       (ph8..ph9; over dead ph1-7 bufs)
    bf16_t* t_b2    = (bf16_t*)(ws);
    bf16_t* WqkvT   = (bf16_t*)(ws + 16777216);
    bf16_t* WprojT  = (bf16_t*)(ws + 17170432);
    bf16_t* Wfc1T   = (bf16_t*)(ws + 17301504);
    bf16_t* Wfc2T   = (bf16_t*)(ws + 18350080);
    float*  ctxp    = (float*)(ws + 19398656);
    float*  ctx     = (float*)(ws + 21495808);
    bf16_t* t_b     = (bf16_t*)(ws + 21757952);
    bf16_t* qkv_b   = (bf16_t*)(ws + 38535168);
    bf16_t* img_b   = (bf16_t*)(ws + 88866816);
    bf16_t* conv_b  = (bf16_t*)(ws + 105644032);
    bf16_t* convT_b = (bf16_t*)(ws + 122421248);
    bf16_t* hidden  = (bf16_t*)(ws + 21757952);

    // ph1: x -> t_b (bf16); weight casts
    transpose_cast<0><<<dim3(N_ / 32, C_ / 32, B_), dim3(32, 8), 0, stream>>>(x, t_b);
    wcastT<<<dim3(768 / 32, C_ / 32), dim3(32, 8), 0, stream>>>(Wqkv, WqkvT, C_, 768);
    wcastT<<<dim3(C_ / 32, C_ / 32), dim3(32, 8), 0, stream>>>(Wproj, WprojT, C_, C_);
    wcastT<<<dim3(CM_ / 32, C_ / 32), dim3(32, 8), 0, stream>>>(Wfc1, Wfc1T, C_, CM_);
    wcastT<<<dim3(C_ / 32, CM_ / 32), dim3(32, 8), 0, stream>>>(Wfc2, Wfc2T, CM_, C_);

    // ph2: qkv_b = bf16(t @ Wqkv + bqkv)
    gemm_bf16<4><<<dim3(768 / 128, M_ / 128), 256, 0, stream>>>(
        t_b, WqkvT, bqkv, nullptr, qkv_b, M_, 768, C_,
        nullptr, nullptr, nullptr, nullptr, nullptr, nullptr);

    // ph3: ctx = relu(k)^T v
    ctx_partial<<<dim3(8, B_ * NH_), 256, 0, stream>>>(qkv_b, ctxp);
    ctx_reduce<<<256, 256, 0, stream>>>(ctxp, ctx);

    // ph4: img_b = (relu(q)*scale) @ ctx   [B,C,N] bf16
    attn_out<<<dim3(N_ / 64, B_ * NH_), 256, 0, stream>>>(qkv_b, ctx, img_b);

    // ph5: depthwise conv (bf16 -> bf16)
    dwconv3x3<<<B_ * C_, 256, 0, stream>>>(img_b, dw_w, dw_b, conv_b);

    // ph6: conv_b -> convT_b (bf16 [B,N,C])
    transpose_cast<1><<<dim3(N_ / 32, C_ / 32, B_), dim3(32, 8), 0, stream>>>(conv_b, convT_b);

    // ph7: t_b2 = repbn1(t_b + convT @ Wproj + bproj)   (bf16)
    gemm_bf16<1><<<dim3(C_ / 128, M_ / 128), 256, 0, stream>>>(
        convT_b, WprojT, bproj, nullptr, t_b2, M_, C_, C_,
        t_b, bn1_g, bn1_b, bn1_m, bn1_v, alpha1);

    // ph8: hidden = gelu(t_b2 @ Wfc1 + bfc1)   (full M)
    gemm_bf16<2><<<dim3(CM_ / 128, M_ / 128), 256, 0, stream>>>(
        t_b2, Wfc1T, bfc1, nullptr, hidden, M_, CM_, C_,
        nullptr, nullptr, nullptr, nullptr, nullptr, nullptr);

    // ph9: out = repbn2(t_b2 + hidden @ Wfc2 + bfc2), transposed to [B,C,H,W]
    gemm_bf16<3><<<dim3(C_ / 128, M_ / 128), 256, 0, stream>>>(
        hidden, Wfc2T, bfc2, out, nullptr, M_, C_, CM_,
        t_b2, bn2_g, bn2_b, bn2_m, bn2_v, alpha2);
}

// Round 8
// 338.043 us; speedup vs baseline: 1.3097x; 1.0133x over previous
//
#include <hip/hip_runtime.h>
#include <hip/hip_bf16.h>
#include <math.h>

// Problem constants
constexpr int B_ = 8, C_ = 256, H_ = 64, W_ = 64;
constexpr int N_ = H_ * W_;          // 4096
constexpr int NH_ = 8;
constexpr int CM_ = 2048;
constexpr int M_ = B_ * N_;          // 32768
constexpr float EPS_ = 1e-5f;

typedef __bf16 bf16_t;
typedef bf16_t bf16x4 __attribute__((ext_vector_type(4)));
typedef bf16_t bf16x8 __attribute__((ext_vector_type(8)));
typedef float f32x4 __attribute__((ext_vector_type(4)));

__device__ inline bf16_t f2b(float f) {
    __hip_bfloat16 h = __float2bfloat16(f);
    return *reinterpret_cast<bf16_t*>(&h);
}
__device__ inline float b2f(bf16_t b) {
    unsigned short u = *reinterpret_cast<unsigned short*>(&b);
    unsigned int x = (unsigned int)u << 16;
    return *reinterpret_cast<float*>(&x);
}
__device__ inline float gelu_ap(float y) {
    float u = y * (0.7978845608f + 0.0356774081f * y * y);
    float e = __expf(2.0f * u);
    return y - y * __builtin_amdgcn_rcpf(e + 1.0f);
}

#define GLOAD_LDS16(gptr, lptr)                                                     \
    __builtin_amdgcn_global_load_lds(                                               \
        (const __attribute__((address_space(1))) void*)(gptr),                      \
        (__attribute__((address_space(3))) void*)(lptr), 16, 0, 0)

// ---------------------------------------------------------------------------
// Transpose [B,C,N] -> [B,N,C] (bf16 out). MODE 0: f32 in; MODE 1: bf16 in.
template <int MODE>
__global__ void transpose_cast(const void* __restrict__ in_, bf16_t* __restrict__ outb) {
    __shared__ float tile[32][33];
    int b  = blockIdx.z;
    int n0 = blockIdx.x * 32;
    int c0 = blockIdx.y * 32;
    int tx = threadIdx.x, ty = threadIdx.y;
#pragma unroll
    for (int i = ty; i < 32; i += 8) {
        size_t off = (size_t)b * C_ * N_ + (size_t)(c0 + i) * N_ + n0 + tx;
        tile[i][tx] = (MODE == 0) ? ((const float*)in_)[off] : b2f(((const bf16_t*)in_)[off]);
    }
    __syncthreads();
#pragma unroll
    for (int i = ty; i < 32; i += 8) {
        size_t off = (size_t)b * N_ * C_ + (size_t)(n0 + i) * C_ + c0 + tx;
        outb[off] = f2b(tile[tx][i]);
    }
}

// ---------------------------------------------------------------------------
// Weight cast + transpose: W [K,N] f32 -> Wt [N,K] bf16
__global__ void wcastT(const float* __restrict__ W, bf16_t* __restrict__ Wt,
                       int K, int N) {
    __shared__ float tile[32][33];
    int k0 = blockIdx.y * 32, n0 = blockIdx.x * 32;
    int tx = threadIdx.x, ty = threadIdx.y;
#pragma unroll
    for (int i = ty; i < 32; i += 8)
        tile[i][tx] = W[(size_t)(k0 + i) * N + n0 + tx];
    __syncthreads();
#pragma unroll
    for (int i = ty; i < 32; i += 8)
        Wt[(size_t)(n0 + i) * K + k0 + tx] = f2b(tile[tx][i]);
}

// ---------------------------------------------------------------------------
// Swapped-operand bf16 MFMA GEMM: out[m, ch] = Act[m,:] . Wt[ch,:] + bias[ch].
// A-operand = weight rows (ch), B-operand = activation rows (m) -> each lane's
// 4 C/D regs are 4 CONSECUTIVE out-channels at fixed m: native bf16x4 stores,
// no LDS epilogue. 128(ch) x 128(m) tile, BK=64, 4 waves, XCD swizzle.
//  EPI 4: acc+bias -> Cb bf16 [M,N] row-major
//  EPI 2: gelu(acc+bias) -> Cb
//  EPI 1: z=b2f(tres)+acc+bias; repbn1 -> Cb
template <int EPI>
__global__ __launch_bounds__(256)
void gemm_swp(const bf16_t* __restrict__ Wt, const bf16_t* __restrict__ Act,
              const float* __restrict__ bias, bf16_t* __restrict__ Cb,
              int M, int N, int K,
              const bf16_t* __restrict__ tres_b,
              const float* __restrict__ g, const float* __restrict__ bb,
              const float* __restrict__ mm, const float* __restrict__ vv,
              const float* __restrict__ alpha) {
    __shared__ bf16x8 ldsv[2048];          // 32 KB: W = [0,1024), Act = [1024,2048)
    char* lds = (char*)ldsv;

    int tid  = threadIdx.x;
    int lane = tid & 63;
    int w    = tid >> 6;
    int wi   = w >> 1, wj = w & 1;         // wi: ch 64-block, wj: m 64-block

    // XCD-aware bijective swizzle (nwg % 8 == 0 for all our grids)
    int nwg = gridDim.x * gridDim.y;
    int bid = blockIdx.y * gridDim.x + blockIdx.x;
    int swz = (bid & 7) * (nwg >> 3) + (bid >> 3);
    int bx = swz % gridDim.x, by = swz / gridDim.x;
    int bch = bx * 128, bm = by * 128;

    int rowl = lane & 15, kq = lane >> 4;

    f32x4 acc[4][4] = {};

    for (int k0 = 0; k0 < K; k0 += 64) {
#pragma unroll
        for (int j = 0; j < 4; ++j) {
            int jj = w * 4 + j;
            int msub = jj >> 1, kh = jj & 1;
            const bf16_t* gw = Wt + ((size_t)(bch + msub * 16 + rowl) * K + k0 + kh * 32 + kq * 8);
            GLOAD_LDS16(gw, lds + jj * 1024);
            const bf16_t* ga = Act + ((size_t)(bm + msub * 16 + rowl) * K + k0 + kh * 32 + kq * 8);
            GLOAD_LDS16(ga, lds + 16384 + jj * 1024);
        }
        __syncthreads();
#pragma unroll
        for (int ks = 0; ks < 2; ++ks) {
            bf16x8 wf[4], af[4];
#pragma unroll
            for (int i = 0; i < 4; ++i) wf[i] = ldsv[((wi * 4 + i) * 2 + ks) * 64 + lane];
#pragma unroll
            for (int j = 0; j < 4; ++j) af[j] = ldsv[1024 + ((wj * 4 + j) * 2 + ks) * 64 + lane];
#pragma unroll
            for (int i = 0; i < 4; ++i)
#pragma unroll
                for (int j = 0; j < 4; ++j)
                    acc[i][j] = __builtin_amdgcn_mfma_f32_16x16x32_bf16(wf[i], af[j], acc[i][j], 0, 0, 0);
        }
        __syncthreads();
    }

    float alpha_v = (EPI == 1) ? alpha[0] : 0.f;
#pragma unroll
    for (int i = 0; i < 4; ++i) {
        int ch = bch + wi * 64 + i * 16 + (lane >> 4) * 4;
        f32x4 b4 = *(const f32x4*)(bias + ch);
        f32x4 rs4, B4, m4;
        if (EPI == 1) {
            f32x4 g4 = *(const f32x4*)(g + ch);
            f32x4 v4 = *(const f32x4*)(vv + ch);
            B4 = *(const f32x4*)(bb + ch);
            m4 = *(const f32x4*)(mm + ch);
#pragma unroll
            for (int r = 0; r < 4; ++r) rs4[r] = rsqrtf(v4[r] + EPS_) * g4[r];
        }
#pragma unroll
        for (int j = 0; j < 4; ++j) {
            int m = bm + wj * 64 + j * 16 + (lane & 15);
            f32x4 a = acc[i][j];
            bf16_t ob[4];
            if (EPI == 4) {
#pragma unroll
                for (int r = 0; r < 4; ++r) ob[r] = f2b(a[r] + b4[r]);
            } else if (EPI == 2) {
#pragma unroll
                for (int r = 0; r < 4; ++r) ob[r] = f2b(gelu_ap(a[r] + b4[r]));
            } else {  // EPI 1
                bf16x4 t4 = *(const bf16x4*)(tres_b + (size_t)m * N + ch);
#pragma unroll
                for (int r = 0; r < 4; ++r) {
                    float z = b2f(t4[r]) + a[r] + b4[r];
                    ob[r] = f2b((z - m4[r]) * rs4[r] + B4[r] + alpha_v * z);
                }
            }
            *(bf16x4*)(Cb + (size_t)m * N + ch) = *(bf16x4*)ob;
        }
    }
}

// ---------------------------------------------------------------------------
// Non-swapped bf16 MFMA GEMM, EPI 3 only (fc2): native f32x4 stores to [B,C,N].
__global__ __launch_bounds__(256)
void gemm_bf16(const bf16_t* __restrict__ A, const bf16_t* __restrict__ Bt,
               const float* __restrict__ bias,
               float* __restrict__ Cf,
               int M, int N, int K,
               const bf16_t* __restrict__ tres_b,
               const float* __restrict__ g, const float* __restrict__ bb,
               const float* __restrict__ mm, const float* __restrict__ vv,
               const float* __restrict__ alpha) {
    __shared__ bf16x8 ldsv[2048];          // 32 KB
    char* lds = (char*)ldsv;

    int tid  = threadIdx.x;
    int lane = tid & 63;
    int w    = tid >> 6;
    int wm   = w >> 1, wn = w & 1;

    int nwg = gridDim.x * gridDim.y;
    int bid = blockIdx.y * gridDim.x + blockIdx.x;
    int swz = (bid & 7) * (nwg >> 3) + (bid >> 3);
    int bx = swz % gridDim.x, by = swz / gridDim.x;
    int brow = by * 128, bcol = bx * 128;

    int rowl = lane & 15, kq = lane >> 4;

    f32x4 acc[4][4] = {};

    for (int k0 = 0; k0 < K; k0 += 64) {
#pragma unroll
        for (int j = 0; j < 4; ++j) {
            int jj = w * 4 + j;
            int msub = jj >> 1, kh = jj & 1;
            const bf16_t* ga = A + ((size_t)(brow + msub * 16 + rowl) * K + k0 + kh * 32 + kq * 8);
            GLOAD_LDS16(ga, lds + jj * 1024);
            const bf16_t* gb = Bt + ((size_t)(bcol + msub * 16 + rowl) * K + k0 + kh * 32 + kq * 8);
            GLOAD_LDS16(gb, lds + 16384 + jj * 1024);
        }
        __syncthreads();
#pragma unroll
        for (int ks = 0; ks < 2; ++ks) {
            bf16x8 af[4], bfr[4];
#pragma unroll
            for (int m = 0; m < 4; ++m) af[m] = ldsv[((wm * 4 + m) * 2 + ks) * 64 + lane];
#pragma unroll
            for (int n = 0; n < 4; ++n) bfr[n] = ldsv[1024 + ((wn * 4 + n) * 2 + ks) * 64 + lane];
#pragma unroll
            for (int m = 0; m < 4; ++m)
#pragma unroll
                for (int n = 0; n < 4; ++n)
                    acc[m][n] = __builtin_amdgcn_mfma_f32_16x16x32_bf16(af[m], bfr[n], acc[m][n], 0, 0, 0);
        }
        __syncthreads();
    }

    float alpha_v = alpha[0];
#pragma unroll
    for (int m = 0; m < 4; ++m) {
        int mbase = brow + wm * 64 + m * 16 + (lane >> 4) * 4;
        int bi = mbase >> 12, ni = mbase & (N_ - 1);
#pragma unroll
        for (int n = 0; n < 4; ++n) {
            int col = bcol + wn * 64 + n * 16 + (lane & 15);
            float bv = bias[col];
            float rs = rsqrtf(vv[col] + EPS_) * g[col];
            float bbv = bb[col], mv = mm[col];
            f32x4 o4;
#pragma unroll
            for (int r = 0; r < 4; ++r) {
                float z = b2f(tres_b[(size_t)(mbase + r) * C_ + col]) + acc[m][n][r] + bv;
                o4[r] = (z - mv) * rs + bbv + alpha_v * z;
            }
            *(f32x4*)(Cf + ((size_t)bi * C_ + col) * N_ + ni) = o4;
        }
    }
}

// ---------------------------------------------------------------------------
// ctx partials: ctxp[seg][b*NH+h][d][e] = sum_{n in seg} relu(k[n,d]) * v[n,e]
__global__ void ctx_partial(const bf16_t* __restrict__ qkv, float* __restrict__ ctxp) {
    __shared__ float kb[64][40];
    __shared__ float vb[64][40];
    int seg = blockIdx.x;
    int bh  = blockIdx.y;
    int b = bh >> 3, h = bh & 7;
    int tid = threadIdx.x;
    int d  = tid >> 3;
    int e0 = (tid & 7) * 4;
    int lrow = tid >> 2, lcol = (tid & 3) * 8;
    float acc[4] = {0.f, 0.f, 0.f, 0.f};
    const size_t base = (size_t)b * N_ * 768 + h * 32;
    for (int n0 = seg * 512; n0 < seg * 512 + 512; n0 += 64) {
        size_t ra = base + (size_t)(n0 + lrow) * 768 + lcol;
        bf16x8 kv8 = *(const bf16x8*)(qkv + ra + 256);
        bf16x8 vv8 = *(const bf16x8*)(qkv + ra + 512);
#pragma unroll
        for (int j = 0; j < 8; ++j) {
            kb[lrow][lcol + j] = b2f(kv8[j]);
            vb[lrow][lcol + j] = b2f(vv8[j]);
        }
        __syncthreads();
#pragma unroll
        for (int nl = 0; nl < 64; ++nl) {
            float kv = fmaxf(kb[nl][d], 0.f);
#pragma unroll
            for (int j = 0; j < 4; ++j)
                acc[j] = fmaf(kv, vb[nl][e0 + j], acc[j]);
        }
        __syncthreads();
    }
    float* o = ctxp + ((size_t)seg * 64 + bh) * 1024 + d * 32 + e0;
#pragma unroll
    for (int j = 0; j < 4; ++j) o[j] = acc[j];
}

__global__ void ctx_reduce(const float* __restrict__ ctxp, float* __restrict__ ctx) {
    int idx = blockIdx.x * 256 + threadIdx.x;
    float s = 0.f;
#pragma unroll
    for (int seg = 0; seg < 8; ++seg) s += ctxp[(size_t)seg * 65536 + idx];
    ctx[idx] = s;
}

// ---------------------------------------------------------------------------
__global__ void attn_out(const bf16_t* __restrict__ qkv, const float* __restrict__ ctx,
                         bf16_t* __restrict__ img) {
    __shared__ float qb[64][33];
    __shared__ float cs[32][32];
    int n0 = blockIdx.x * 64;
    int bh = blockIdx.y;
    int b = bh >> 3, h = bh & 7;
    int tid = threadIdx.x;
    const float scale = 0.17677669529663687f;
    {
        float4 vv = ((const float4*)(ctx + (size_t)bh * 1024))[tid];
        ((float4*)&cs[0][0])[tid] = vv;
    }
    const size_t base = (size_t)b * N_ * 768 + h * 32;
    int lrow = tid >> 2, lcol = (tid & 3) * 8;
    {
        bf16x8 q8 = *(const bf16x8*)(qkv + base + (size_t)(n0 + lrow) * 768 + lcol);
#pragma unroll
        for (int j = 0; j < 8; ++j)
            qb[lrow][lcol + j] = fmaxf(b2f(q8[j]), 0.f) * scale;
    }
    __syncthreads();
    int nl = tid & 63, ebase = tid >> 6;
    bf16_t* outp = img + ((size_t)b * C_ + h * 32) * N_ + n0 + nl;
#pragma unroll
    for (int p = 0; p < 8; ++p) {
        int e = ebase + p * 4;
        float s = 0.f;
#pragma unroll
        for (int dd = 0; dd < 32; ++dd)
            s = fmaf(qb[nl][dd], cs[dd][e], s);
        outp[(size_t)e * N_] = f2b(s);
    }
}

// ---------------------------------------------------------------------------
__global__ __launch_bounds__(256)
void dwconv3x3(const bf16_t* __restrict__ img, const float* __restrict__ w,
               const float* __restrict__ bias, bf16_t* __restrict__ out) {
    __shared__ float sp[64][65];
    int bc = blockIdx.x;
    int c  = bc & 255;
    int tid = threadIdx.x;
    const bf16_t* ip = img + (size_t)bc * N_;
#pragma unroll
    for (int l = 0; l < 2; ++l) {
        int flat = (tid + l * 256) * 8;
        int row = flat >> 6, col = flat & 63;
        bf16x8 v8 = *(const bf16x8*)(ip + flat);
#pragma unroll
        for (int j = 0; j < 8; ++j) sp[row][col + j] = b2f(v8[j]);
    }
    float wv[9];
#pragma unroll
    for (int j = 0; j < 9; ++j) wv[j] = w[c * 9 + j];
    float bv = bias[c];
    __syncthreads();

    int y = tid >> 2, x0 = (tid & 3) * 16;
    float o[16];
#pragma unroll
    for (int i = 0; i < 16; ++i) o[i] = bv;
#pragma unroll
    for (int dy = -1; dy <= 1; ++dy) {
        int yy = y + dy;
        if (yy < 0 || yy > 63) continue;
#pragma unroll
        for (int dx = -1; dx <= 1; ++dx) {
            float wgt = wv[(dy + 1) * 3 + dx + 1];
#pragma unroll
            for (int i = 0; i < 16; ++i) {
                int xx = x0 + i + dx;
                float val = (xx < 0 || xx > 63) ? 0.f : sp[yy][xx];
                o[i] = fmaf(wgt, val, o[i]);
            }
        }
    }
    bf16_t ob[16];
#pragma unroll
    for (int i = 0; i < 16; ++i) ob[i] = f2b(o[i]);
    *(bf16x8*)(out + (size_t)bc * N_ + y * 64 + x0)     = *(bf16x8*)&ob[0];
    *(bf16x8*)(out + (size_t)bc * N_ + y * 64 + x0 + 8) = *(bf16x8*)&ob[8];
}

// ---------------------------------------------------------------------------
extern "C" void kernel_launch(void* const* d_in, const int* in_sizes, int n_in,
                              void* d_out, int out_size, void* d_ws, size_t ws_size,
                              hipStream_t stream) {
    const float* x     = (const float*)d_in[0];
    const float* Wqkv  = (const float*)d_in[1];
    const float* bqkv  = (const float*)d_in[2];
    const float* dw_w  = (const float*)d_in[3];
    const float* dw_b  = (const float*)d_in[4];
    const float* Wproj = (const float*)d_in[5];
    const float* bproj = (const float*)d_in[6];
    const float* bn1_g = (const float*)d_in[7];
    const float* bn1_b = (const float*)d_in[8];
    const float* bn1_m = (const float*)d_in[9];
    const float* bn1_v = (const float*)d_in[10];
    const float* alpha1= (const float*)d_in[11];
    const float* Wfc1  = (const float*)d_in[12];
    const float* bfc1  = (const float*)d_in[13];
    const float* Wfc2  = (const float*)d_in[14];
    const float* bfc2  = (const float*)d_in[15];
    const float* bn2_g = (const float*)d_in[16];
    const float* bn2_b = (const float*)d_in[17];
    const float* bn2_m = (const float*)d_in[18];
    const float* bn2_v = (const float*)d_in[19];
    const float* alpha2= (const float*)d_in[20];
    float* out = (float*)d_out;

    char* ws = (char*)d_ws;
    // Workspace layout (bytes), peak 155,975,680 <= proven 170,131,456:
    bf16_t* t_b2    = (bf16_t*)(ws);
    bf16_t* WqkvT   = (bf16_t*)(ws + 16777216);
    bf16_t* WprojT  = (bf16_t*)(ws + 17170432);
    bf16_t* Wfc1T   = (bf16_t*)(ws + 17301504);
    bf16_t* Wfc2T   = (bf16_t*)(ws + 18350080);
    float*  ctxp    = (float*)(ws + 19398656);
    float*  ctx     = (float*)(ws + 21495808);
    bf16_t* t_b     = (bf16_t*)(ws + 21757952);
    bf16_t* qkv_b   = (bf16_t*)(ws + 38535168);
    bf16_t* img_b   = (bf16_t*)(ws + 88866816);
    bf16_t* conv_b  = (bf16_t*)(ws + 105644032);
    bf16_t* convT_b = (bf16_t*)(ws + 122421248);
    bf16_t* hidden  = (bf16_t*)(ws + 21757952);   // over dead ph1-7 bufs

    // ph1: x -> t_b (bf16); weight casts
    transpose_cast<0><<<dim3(N_ / 32, C_ / 32, B_), dim3(32, 8), 0, stream>>>(x, t_b);
    wcastT<<<dim3(768 / 32, C_ / 32), dim3(32, 8), 0, stream>>>(Wqkv, WqkvT, C_, 768);
    wcastT<<<dim3(C_ / 32, C_ / 32), dim3(32, 8), 0, stream>>>(Wproj, WprojT, C_, C_);
    wcastT<<<dim3(CM_ / 32, C_ / 32), dim3(32, 8), 0, stream>>>(Wfc1, Wfc1T, C_, CM_);
    wcastT<<<dim3(C_ / 32, CM_ / 32), dim3(32, 8), 0, stream>>>(Wfc2, Wfc2T, CM_, C_);

    // ph2: qkv_b = bf16(t @ Wqkv + bqkv)   (swapped)
    gemm_swp<4><<<dim3(768 / 128, M_ / 128), 256, 0, stream>>>(
        WqkvT, t_b, bqkv, qkv_b, M_, 768, C_,
        nullptr, nullptr, nullptr, nullptr, nullptr, nullptr);

    // ph3: ctx = relu(k)^T v
    ctx_partial<<<dim3(8, B_ * NH_), 256, 0, stream>>>(qkv_b, ctxp);
    ctx_reduce<<<256, 256, 0, stream>>>(ctxp, ctx);

    // ph4: img_b = (relu(q)*scale) @ ctx   [B,C,N] bf16
    attn_out<<<dim3(N_ / 64, B_ * NH_), 256, 0, stream>>>(qkv_b, ctx, img_b);

    // ph5: depthwise conv (bf16 -> bf16)
    dwconv3x3<<<B_ * C_, 256, 0, stream>>>(img_b, dw_w, dw_b, conv_b);

    // ph6: conv_b -> convT_b (bf16 [B,N,C])
    transpose_cast<1><<<dim3(N_ / 32, C_ / 32, B_), dim3(32, 8), 0, stream>>>(conv_b, convT_b);

    // ph7: t_b2 = repbn1(t_b + convT @ Wproj + bproj)   (swapped)
    gemm_swp<1><<<dim3(C_ / 128, M_ / 128), 256, 0, stream>>>(
        WprojT, convT_b, bproj, t_b2, M_, C_, C_,
        t_b, bn1_g, bn1_b, bn1_m, bn1_v, alpha1);

    // ph8: hidden = gelu(t_b2 @ Wfc1 + bfc1)   (swapped)
    gemm_swp<2><<<dim3(CM_ / 128, M_ / 128), 256, 0, stream>>>(
        Wfc1T, t_b2, bfc1, hidden, M_, CM_, C_,
        nullptr, nullptr, nullptr, nullptr, nullptr, nullptr);

    // ph9: out = repbn2(t_b2 + hidden @ Wfc2 + bfc2), transposed to [B,C,H,W]
    gemm_bf16<<<dim3(C_ / 128, M_ / 128), 256, 0, stream>>>(
        hidden, Wfc2T, bfc2, out, M_, C_, CM_,
        t_b2, bn2_g, bn2_b, bn2_m, bn2_v, alpha2);
}

// Round 9
// 332.150 us; speedup vs baseline: 1.3329x; 1.0177x over previous
//
#include <hip/hip_runtime.h>
#include <hip/hip_bf16.h>
#include <math.h>

// Problem constants
constexpr int B_ = 8, C_ = 256, H_ = 64, W_ = 64;
constexpr int N_ = H_ * W_;          // 4096
constexpr int NH_ = 8;
constexpr int CM_ = 2048;
constexpr int M_ = B_ * N_;          // 32768
constexpr float EPS_ = 1e-5f;

typedef __bf16 bf16_t;
typedef bf16_t bf16x4 __attribute__((ext_vector_type(4)));
typedef bf16_t bf16x8 __attribute__((ext_vector_type(8)));
typedef float f32x4 __attribute__((ext_vector_type(4)));

__device__ inline bf16_t f2b(float f) {
    __hip_bfloat16 h = __float2bfloat16(f);
    return *reinterpret_cast<bf16_t*>(&h);
}
__device__ inline float b2f(bf16_t b) {
    unsigned short u = *reinterpret_cast<unsigned short*>(&b);
    unsigned int x = (unsigned int)u << 16;
    return *reinterpret_cast<float*>(&x);
}
__device__ inline float gelu_ap(float y) {
    float u = y * (0.7978845608f + 0.0356774081f * y * y);
    float e = __expf(2.0f * u);
    return y - y * __builtin_amdgcn_rcpf(e + 1.0f);
}

#define GLOAD_LDS16(gptr, lptr)                                                     \
    __builtin_amdgcn_global_load_lds(                                               \
        (const __attribute__((address_space(1))) void*)(gptr),                      \
        (__attribute__((address_space(3))) void*)(lptr), 16, 0, 0)

// ---------------------------------------------------------------------------
// Merged prep: x [B,C,N] -> t_b [B,N,C] bf16, plus 4 weight cast+transposes.
// All sub-jobs use block (32,8).
__global__ __launch_bounds__(256)
void prep(const float* __restrict__ x, bf16_t* __restrict__ t_b,
          const float* __restrict__ Wqkv, bf16_t* __restrict__ WqkvT,
          const float* __restrict__ Wproj, bf16_t* __restrict__ WprojT,
          const float* __restrict__ Wfc1, bf16_t* __restrict__ Wfc1T,
          const float* __restrict__ Wfc2, bf16_t* __restrict__ Wfc2T) {
    __shared__ float tile[32][33];
    int id = blockIdx.x;
    int tx = threadIdx.x, ty = threadIdx.y;

    const float* src;
    bf16_t* dst;
    int K, N, k0, n0;
    size_t soff, doff;

    if (id < 8192) {               // transpose x -> t_b (per batch b)
        int b = id >> 10, rem = id & 1023;
        int nn = (rem & 127) * 32, cc = (rem >> 7) * 32;
        src = x; dst = t_b; K = 0; N = 0;
        // load tile[c][n]
#pragma unroll
        for (int i = ty; i < 32; i += 8)
            tile[i][tx] = x[(size_t)b * C_ * N_ + (size_t)(cc + i) * N_ + nn + tx];
        __syncthreads();
#pragma unroll
        for (int i = ty; i < 32; i += 8)
            t_b[(size_t)b * N_ * C_ + (size_t)(nn + i) * C_ + cc + tx] = f2b(tile[tx][i]);
        return;
    } else if (id < 8384) {        // Wqkv [256,768] -> [768,256]
        int idw = id - 8192; K = C_; N = 768;
        n0 = (idw % 24) * 32; k0 = (idw / 24) * 32;
        src = Wqkv; dst = WqkvT;
    } else if (id < 8448) {        // Wproj [256,256]
        int idw = id - 8384; K = C_; N = C_;
        n0 = (idw & 7) * 32; k0 = (idw >> 3) * 32;
        src = Wproj; dst = WprojT;
    } else if (id < 8960) {        // Wfc1 [256,2048] -> [2048,256]
        int idw = id - 8448; K = C_; N = CM_;
        n0 = (idw & 63) * 32; k0 = (idw >> 6) * 32;
        src = Wfc1; dst = Wfc1T;
    } else {                       // Wfc2 [2048,256] -> [256,2048]
        int idw = id - 8960; K = CM_; N = C_;
        n0 = (idw & 7) * 32; k0 = (idw >> 3) * 32;
        src = Wfc2; dst = Wfc2T;
    }
#pragma unroll
    for (int i = ty; i < 32; i += 8)
        tile[i][tx] = src[(size_t)(k0 + i) * N + n0 + tx];
    __syncthreads();
#pragma unroll
    for (int i = ty; i < 32; i += 8)
        dst[(size_t)(n0 + i) * K + k0 + tx] = f2b(tile[tx][i]);
}

// ---------------------------------------------------------------------------
// Swapped-operand bf16 MFMA GEMM with double-buffered staging (T3-minimum):
// out[m, ch] = Act[m,:] . Wt[ch,:] + bias[ch]. 128x128 tile, BK=64, 4 waves.
// STAGE(t+1) issued BEFORE compute(t); one __syncthreads per K-step -> the
// vmcnt(0) drain waits loads that had a full compute phase to fly.
//  EPI 4: acc+bias -> Cb bf16 [M,N];  EPI 2: gelu;  EPI 1: repbn1
template <int EPI>
__global__ __launch_bounds__(256)
void gemm_swp(const bf16_t* __restrict__ Wt, const bf16_t* __restrict__ Act,
              const float* __restrict__ bias, bf16_t* __restrict__ Cb,
              int M, int N, int K,
              const bf16_t* __restrict__ tres_b,
              const float* __restrict__ g, const float* __restrict__ bb,
              const float* __restrict__ mm, const float* __restrict__ vv,
              const float* __restrict__ alpha) {
    __shared__ bf16x8 ldsv[4096];          // 64 KB: 2 bufs x (W 16KB | Act 16KB)
    char* lds = (char*)ldsv;

    int tid  = threadIdx.x;
    int lane = tid & 63;
    int w    = tid >> 6;
    int wi   = w >> 1, wj = w & 1;

    int nwg = gridDim.x * gridDim.y;
    int bid = blockIdx.y * gridDim.x + blockIdx.x;
    int swz = (bid & 7) * (nwg >> 3) + (bid >> 3);
    int bx = swz % gridDim.x, by = swz / gridDim.x;
    int bch = bx * 128, bm = by * 128;

    int rowl = lane & 15, kq = lane >> 4;

    const bf16_t* wbase = Wt  + (size_t)(bch + (w >> 1) * 32) * K;   // not used; keep simple below
    (void)wbase;

#define STAGE_SWP(k0, p)                                                             \
    {                                                                                \
        _Pragma("unroll")                                                            \
        for (int j = 0; j < 4; ++j) {                                                \
            int jj = w * 4 + j;                                                      \
            int msub = jj >> 1, kh = jj & 1;                                         \
            const bf16_t* gw = Wt + ((size_t)(bch + msub * 16 + rowl) * K + (k0) +   \
                                     kh * 32 + kq * 8);                              \
            GLOAD_LDS16(gw, lds + (p) * 32768 + jj * 1024);                          \
            const bf16_t* ga = Act + ((size_t)(bm + msub * 16 + rowl) * K + (k0) +   \
                                      kh * 32 + kq * 8);                             \
            GLOAD_LDS16(ga, lds + (p) * 32768 + 16384 + jj * 1024);                  \
        }                                                                            \
    }

    f32x4 acc[4][4] = {};
    int T = K >> 6;

    STAGE_SWP(0, 0);
    __syncthreads();

    for (int t = 0; t < T; ++t) {
        int p = t & 1;
        if (t + 1 < T) STAGE_SWP((t + 1) << 6, p ^ 1);
#pragma unroll
        for (int ks = 0; ks < 2; ++ks) {
            bf16x8 wf[4], af[4];
#pragma unroll
            for (int i = 0; i < 4; ++i) wf[i] = ldsv[p * 2048 + ((wi * 4 + i) * 2 + ks) * 64 + lane];
#pragma unroll
            for (int j = 0; j < 4; ++j) af[j] = ldsv[p * 2048 + 1024 + ((wj * 4 + j) * 2 + ks) * 64 + lane];
#pragma unroll
            for (int i = 0; i < 4; ++i)
#pragma unroll
                for (int j = 0; j < 4; ++j)
                    acc[i][j] = __builtin_amdgcn_mfma_f32_16x16x32_bf16(wf[i], af[j], acc[i][j], 0, 0, 0);
        }
        if (t + 1 < T) __syncthreads();
    }

    float alpha_v = (EPI == 1) ? alpha[0] : 0.f;
#pragma unroll
    for (int i = 0; i < 4; ++i) {
        int ch = bch + wi * 64 + i * 16 + (lane >> 4) * 4;
        f32x4 b4 = *(const f32x4*)(bias + ch);
        f32x4 rs4, B4, m4;
        if (EPI == 1) {
            f32x4 g4 = *(const f32x4*)(g + ch);
            f32x4 v4 = *(const f32x4*)(vv + ch);
            B4 = *(const f32x4*)(bb + ch);
            m4 = *(const f32x4*)(mm + ch);
#pragma unroll
            for (int r = 0; r < 4; ++r) rs4[r] = rsqrtf(v4[r] + EPS_) * g4[r];
        }
#pragma unroll
        for (int j = 0; j < 4; ++j) {
            int m = bm + wj * 64 + j * 16 + (lane & 15);
            f32x4 a = acc[i][j];
            bf16_t ob[4];
            if (EPI == 4) {
#pragma unroll
                for (int r = 0; r < 4; ++r) ob[r] = f2b(a[r] + b4[r]);
            } else if (EPI == 2) {
#pragma unroll
                for (int r = 0; r < 4; ++r) ob[r] = f2b(gelu_ap(a[r] + b4[r]));
            } else {  // EPI 1
                bf16x4 t4 = *(const bf16x4*)(tres_b + (size_t)m * N + ch);
#pragma unroll
                for (int r = 0; r < 4; ++r) {
                    float z = b2f(t4[r]) + a[r] + b4[r];
                    ob[r] = f2b((z - m4[r]) * rs4[r] + B4[r] + alpha_v * z);
                }
            }
            *(bf16x4*)(Cb + (size_t)m * N + ch) = *(bf16x4*)ob;
        }
    }
}

// ---------------------------------------------------------------------------
// Non-swapped bf16 MFMA GEMM, EPI3 (fc2) with double-buffered staging:
// native f32x4 stores to [B,C,N].
__global__ __launch_bounds__(256)
void gemm_bf16(const bf16_t* __restrict__ A, const bf16_t* __restrict__ Bt,
               const float* __restrict__ bias,
               float* __restrict__ Cf,
               int M, int N, int K,
               const bf16_t* __restrict__ tres_b,
               const float* __restrict__ g, const float* __restrict__ bb,
               const float* __restrict__ mm, const float* __restrict__ vv,
               const float* __restrict__ alpha) {
    __shared__ bf16x8 ldsv[4096];          // 64 KB
    char* lds = (char*)ldsv;

    int tid  = threadIdx.x;
    int lane = tid & 63;
    int w    = tid >> 6;
    int wm   = w >> 1, wn = w & 1;

    int nwg = gridDim.x * gridDim.y;
    int bid = blockIdx.y * gridDim.x + blockIdx.x;
    int swz = (bid & 7) * (nwg >> 3) + (bid >> 3);
    int bx = swz % gridDim.x, by = swz / gridDim.x;
    int brow = by * 128, bcol = bx * 128;

    int rowl = lane & 15, kq = lane >> 4;

#define STAGE_NSW(k0, p)                                                             \
    {                                                                                \
        _Pragma("unroll")                                                            \
        for (int j = 0; j < 4; ++j) {                                                \
            int jj = w * 4 + j;                                                      \
            int msub = jj >> 1, kh = jj & 1;                                         \
            const bf16_t* ga = A + ((size_t)(brow + msub * 16 + rowl) * K + (k0) +   \
                                    kh * 32 + kq * 8);                               \
            GLOAD_LDS16(ga, lds + (p) * 32768 + jj * 1024);                          \
            const bf16_t* gb = Bt + ((size_t)(bcol + msub * 16 + rowl) * K + (k0) +  \
                                     kh * 32 + kq * 8);                              \
            GLOAD_LDS16(gb, lds + (p) * 32768 + 16384 + jj * 1024);                  \
        }                                                                            \
    }

    f32x4 acc[4][4] = {};
    int T = K >> 6;

    STAGE_NSW(0, 0);
    __syncthreads();

    for (int t = 0; t < T; ++t) {
        int p = t & 1;
        if (t + 1 < T) STAGE_NSW((t + 1) << 6, p ^ 1);
#pragma unroll
        for (int ks = 0; ks < 2; ++ks) {
            bf16x8 af[4], bfr[4];
#pragma unroll
            for (int m = 0; m < 4; ++m) af[m] = ldsv[p * 2048 + ((wm * 4 + m) * 2 + ks) * 64 + lane];
#pragma unroll
            for (int n = 0; n < 4; ++n) bfr[n] = ldsv[p * 2048 + 1024 + ((wn * 4 + n) * 2 + ks) * 64 + lane];
#pragma unroll
            for (int m = 0; m < 4; ++m)
#pragma unroll
                for (int n = 0; n < 4; ++n)
                    acc[m][n] = __builtin_amdgcn_mfma_f32_16x16x32_bf16(af[m], bfr[n], acc[m][n], 0, 0, 0);
        }
        if (t + 1 < T) __syncthreads();
    }

    float alpha_v = alpha[0];
#pragma unroll
    for (int m = 0; m < 4; ++m) {
        int mbase = brow + wm * 64 + m * 16 + (lane >> 4) * 4;
        int bi = mbase >> 12, ni = mbase & (N_ - 1);
#pragma unroll
        for (int n = 0; n < 4; ++n) {
            int col = bcol + wn * 64 + n * 16 + (lane & 15);
            float bv = bias[col];
            float rs = rsqrtf(vv[col] + EPS_) * g[col];
            float bbv = bb[col], mv = mm[col];
            f32x4 o4;
#pragma unroll
            for (int r = 0; r < 4; ++r) {
                float z = b2f(tres_b[(size_t)(mbase + r) * C_ + col]) + acc[m][n][r] + bv;
                o4[r] = (z - mv) * rs + bbv + alpha_v * z;
            }
            *(f32x4*)(Cf + ((size_t)bi * C_ + col) * N_ + ni) = o4;
        }
    }
}

// ---------------------------------------------------------------------------
// Transpose [B,C,N] -> [B,N,C] bf16 (conv output path)
__global__ void transpose_b(const bf16_t* __restrict__ in_, bf16_t* __restrict__ outb) {
    __shared__ float tile[32][33];
    int b  = blockIdx.z;
    int n0 = blockIdx.x * 32;
    int c0 = blockIdx.y * 32;
    int tx = threadIdx.x, ty = threadIdx.y;
#pragma unroll
    for (int i = ty; i < 32; i += 8)
        tile[i][tx] = b2f(in_[(size_t)b * C_ * N_ + (size_t)(c0 + i) * N_ + n0 + tx]);
    __syncthreads();
#pragma unroll
    for (int i = ty; i < 32; i += 8)
        outb[(size_t)b * N_ * C_ + (size_t)(n0 + i) * C_ + c0 + tx] = f2b(tile[tx][i]);
}

// ---------------------------------------------------------------------------
// ctx partials: ctxp[seg][b*NH+h][d][e] = sum_{n in seg} relu(k[n,d]) * v[n,e]
__global__ void ctx_partial(const bf16_t* __restrict__ qkv, float* __restrict__ ctxp) {
    __shared__ float kb[64][40];
    __shared__ float vb[64][40];
    int seg = blockIdx.x;
    int bh  = blockIdx.y;
    int b = bh >> 3, h = bh & 7;
    int tid = threadIdx.x;
    int d  = tid >> 3;
    int e0 = (tid & 7) * 4;
    int lrow = tid >> 2, lcol = (tid & 3) * 8;
    float acc[4] = {0.f, 0.f, 0.f, 0.f};
    const size_t base = (size_t)b * N_ * 768 + h * 32;
    for (int n0 = seg * 512; n0 < seg * 512 + 512; n0 += 64) {
        size_t ra = base + (size_t)(n0 + lrow) * 768 + lcol;
        bf16x8 kv8 = *(const bf16x8*)(qkv + ra + 256);
        bf16x8 vv8 = *(const bf16x8*)(qkv + ra + 512);
#pragma unroll
        for (int j = 0; j < 8; ++j) {
            kb[lrow][lcol + j] = b2f(kv8[j]);
            vb[lrow][lcol + j] = b2f(vv8[j]);
        }
        __syncthreads();
#pragma unroll
        for (int nl = 0; nl < 64; ++nl) {
            float kv = fmaxf(kb[nl][d], 0.f);
#pragma unroll
            for (int j = 0; j < 4; ++j)
                acc[j] = fmaf(kv, vb[nl][e0 + j], acc[j]);
        }
        __syncthreads();
    }
    float* o = ctxp + ((size_t)seg * 64 + bh) * 1024 + d * 32 + e0;
#pragma unroll
    for (int j = 0; j < 4; ++j) o[j] = acc[j];
}

__global__ void ctx_reduce(const float* __restrict__ ctxp, float* __restrict__ ctx) {
    int idx = blockIdx.x * 256 + threadIdx.x;
    float s = 0.f;
#pragma unroll
    for (int seg = 0; seg < 8; ++seg) s += ctxp[(size_t)seg * 65536 + idx];
    ctx[idx] = s;
}

// ---------------------------------------------------------------------------
__global__ void attn_out(const bf16_t* __restrict__ qkv, const float* __restrict__ ctx,
                         bf16_t* __restrict__ img) {
    __shared__ float qb[64][33];
    __shared__ float cs[32][32];
    int n0 = blockIdx.x * 64;
    int bh = blockIdx.y;
    int b = bh >> 3, h = bh & 7;
    int tid = threadIdx.x;
    const float scale = 0.17677669529663687f;
    {
        float4 vv = ((const float4*)(ctx + (size_t)bh * 1024))[tid];
        ((float4*)&cs[0][0])[tid] = vv;
    }
    const size_t base = (size_t)b * N_ * 768 + h * 32;
    int lrow = tid >> 2, lcol = (tid & 3) * 8;
    {
        bf16x8 q8 = *(const bf16x8*)(qkv + base + (size_t)(n0 + lrow) * 768 + lcol);
#pragma unroll
        for (int j = 0; j < 8; ++j)
            qb[lrow][lcol + j] = fmaxf(b2f(q8[j]), 0.f) * scale;
    }
    __syncthreads();
    int nl = tid & 63, ebase = tid >> 6;
    bf16_t* outp = img + ((size_t)b * C_ + h * 32) * N_ + n0 + nl;
#pragma unroll
    for (int p = 0; p < 8; ++p) {
        int e = ebase + p * 4;
        float s = 0.f;
#pragma unroll
        for (int dd = 0; dd < 32; ++dd)
            s = fmaf(qb[nl][dd], cs[dd][e], s);
        outp[(size_t)e * N_] = f2b(s);
    }
}

// ---------------------------------------------------------------------------
__global__ __launch_bounds__(256)
void dwconv3x3(const bf16_t* __restrict__ img, const float* __restrict__ w,
               const float* __restrict__ bias, bf16_t* __restrict__ out) {
    __shared__ float sp[64][65];
    int bc = blockIdx.x;
    int c  = bc & 255;
    int tid = threadIdx.x;
    const bf16_t* ip = img + (size_t)bc * N_;
#pragma unroll
    for (int l = 0; l < 2; ++l) {
        int flat = (tid + l * 256) * 8;
        int row = flat >> 6, col = flat & 63;
        bf16x8 v8 = *(const bf16x8*)(ip + flat);
#pragma unroll
        for (int j = 0; j < 8; ++j) sp[row][col + j] = b2f(v8[j]);
    }
    float wv[9];
#pragma unroll
    for (int j = 0; j < 9; ++j) wv[j] = w[c * 9 + j];
    float bv = bias[c];
    __syncthreads();

    int y = tid >> 2, x0 = (tid & 3) * 16;
    float o[16];
#pragma unroll
    for (int i = 0; i < 16; ++i) o[i] = bv;
#pragma unroll
    for (int dy = -1; dy <= 1; ++dy) {
        int yy = y + dy;
        if (yy < 0 || yy > 63) continue;
#pragma unroll
        for (int dx = -1; dx <= 1; ++dx) {
            float wgt = wv[(dy + 1) * 3 + dx + 1];
#pragma unroll
            for (int i = 0; i < 16; ++i) {
                int xx = x0 + i + dx;
                float val = (xx < 0 || xx > 63) ? 0.f : sp[yy][xx];
                o[i] = fmaf(wgt, val, o[i]);
            }
        }
    }
    bf16_t ob[16];
#pragma unroll
    for (int i = 0; i < 16; ++i) ob[i] = f2b(o[i]);
    *(bf16x8*)(out + (size_t)bc * N_ + y * 64 + x0)     = *(bf16x8*)&ob[0];
    *(bf16x8*)(out + (size_t)bc * N_ + y * 64 + x0 + 8) = *(bf16x8*)&ob[8];
}

// ---------------------------------------------------------------------------
extern "C" void kernel_launch(void* const* d_in, const int* in_sizes, int n_in,
                              void* d_out, int out_size, void* d_ws, size_t ws_size,
                              hipStream_t stream) {
    const float* x     = (const float*)d_in[0];
    const float* Wqkv  = (const float*)d_in[1];
    const float* bqkv  = (const float*)d_in[2];
    const float* dw_w  = (const float*)d_in[3];
    const float* dw_b  = (const float*)d_in[4];
    const float* Wproj = (const float*)d_in[5];
    const float* bproj = (const float*)d_in[6];
    const float* bn1_g = (const float*)d_in[7];
    const float* bn1_b = (const float*)d_in[8];
    const float* bn1_m = (const float*)d_in[9];
    const float* bn1_v = (const float*)d_in[10];
    const float* alpha1= (const float*)d_in[11];
    const float* Wfc1  = (const float*)d_in[12];
    const float* bfc1  = (const float*)d_in[13];
    const float* Wfc2  = (const float*)d_in[14];
    const float* bfc2  = (const float*)d_in[15];
    const float* bn2_g = (const float*)d_in[16];
    const float* bn2_b = (const float*)d_in[17];
    const float* bn2_m = (const float*)d_in[18];
    const float* bn2_v = (const float*)d_in[19];
    const float* alpha2= (const float*)d_in[20];
    float* out = (float*)d_out;

    char* ws = (char*)d_ws;
    bf16_t* t_b2    = (bf16_t*)(ws);
    bf16_t* WqkvT   = (bf16_t*)(ws + 16777216);
    bf16_t* WprojT  = (bf16_t*)(ws + 17170432);
    bf16_t* Wfc1T   = (bf16_t*)(ws + 17301504);
    bf16_t* Wfc2T   = (bf16_t*)(ws + 18350080);
    float*  ctxp    = (float*)(ws + 19398656);
    float*  ctx     = (float*)(ws + 21495808);
    bf16_t* t_b     = (bf16_t*)(ws + 21757952);
    bf16_t* qkv_b   = (bf16_t*)(ws + 38535168);
    bf16_t* img_b   = (bf16_t*)(ws + 88866816);
    bf16_t* conv_b  = (bf16_t*)(ws + 105644032);
    bf16_t* convT_b = (bf16_t*)(ws + 122421248);
    bf16_t* hidden  = (bf16_t*)(ws + 21757952);   // over dead ph1-7 bufs

    // ph1: merged prep (transpose x + all 4 weight casts)
    prep<<<9472, dim3(32, 8), 0, stream>>>(x, t_b, Wqkv, WqkvT, Wproj, WprojT,
                                           Wfc1, Wfc1T, Wfc2, Wfc2T);

    // ph2: qkv_b = bf16(t @ Wqkv + bqkv)   (swapped, dbuf)
    gemm_swp<4><<<dim3(768 / 128, M_ / 128), 256, 0, stream>>>(
        WqkvT, t_b, bqkv, qkv_b, M_, 768, C_,
        nullptr, nullptr, nullptr, nullptr, nullptr, nullptr);

    // ph3: ctx = relu(k)^T v
    ctx_partial<<<dim3(8, B_ * NH_), 256, 0, stream>>>(qkv_b, ctxp);
    ctx_reduce<<<256, 256, 0, stream>>>(ctxp, ctx);

    // ph4: img_b = (relu(q)*scale) @ ctx   [B,C,N] bf16
    attn_out<<<dim3(N_ / 64, B_ * NH_), 256, 0, stream>>>(qkv_b, ctx, img_b);

    // ph5: depthwise conv (bf16 -> bf16)
    dwconv3x3<<<B_ * C_, 256, 0, stream>>>(img_b, dw_w, dw_b, conv_b);

    // ph6: conv_b -> convT_b (bf16 [B,N,C])
    transpose_b<<<dim3(N_ / 32, C_ / 32, B_), dim3(32, 8), 0, stream>>>(conv_b, convT_b);

    // ph7: t_b2 = repbn1(t_b + convT @ Wproj + bproj)   (swapped, dbuf)
    gemm_swp<1><<<dim3(C_ / 128, M_ / 128), 256, 0, stream>>>(
        WprojT, convT_b, bproj, t_b2, M_, C_, C_,
        t_b, bn1_g, bn1_b, bn1_m, bn1_v, alpha1);

    // ph8: hidden = gelu(t_b2 @ Wfc1 + bfc1)   (swapped, dbuf)
    gemm_swp<2><<<dim3(CM_ / 128, M_ / 128), 256, 0, stream>>>(
        Wfc1T, t_b2, bfc1, hidden, M_, CM_, C_,
        nullptr, nullptr, nullptr, nullptr, nullptr, nullptr);

    // ph9: out = repbn2(t_b2 + hidden @ Wfc2 + bfc2), transposed to [B,C,H,W]
    gemm_bf16<<<dim3(C_ / 128, M_ / 128), 256, 0, stream>>>(
        hidden, Wfc2T, bfc2, out, M_, C_, CM_,
        t_b2, bn2_g, bn2_b, bn2_m, bn2_v, alpha2);
}

// Round 10
// 303.706 us; speedup vs baseline: 1.4578x; 1.0937x over previous
//
#include <hip/hip_runtime.h>
#include <hip/hip_bf16.h>
#include <math.h>

// Problem constants
constexpr int B_ = 8, C_ = 256, H_ = 64, W_ = 64;
constexpr int N_ = H_ * W_;          // 4096
constexpr int NH_ = 8;
constexpr int CM_ = 2048;
constexpr int M_ = B_ * N_;          // 32768
constexpr float EPS_ = 1e-5f;

typedef __bf16 bf16_t;
typedef bf16_t bf16x4 __attribute__((ext_vector_type(4)));
typedef bf16_t bf16x8 __attribute__((ext_vector_type(8)));
typedef float f32x4 __attribute__((ext_vector_type(4)));

__device__ inline bf16_t f2b(float f) {
    __hip_bfloat16 h = __float2bfloat16(f);
    return *reinterpret_cast<bf16_t*>(&h);
}
__device__ inline float b2f(bf16_t b) {
    unsigned short u = *reinterpret_cast<unsigned short*>(&b);
    unsigned int x = (unsigned int)u << 16;
    return *reinterpret_cast<float*>(&x);
}
__device__ inline unsigned pk2(float lo, float hi) {
    bf16_t l = f2b(lo), h = f2b(hi);
    unsigned short ls = *reinterpret_cast<unsigned short*>(&l);
    unsigned short hs = *reinterpret_cast<unsigned short*>(&h);
    return ((unsigned)hs << 16) | (unsigned)ls;
}
__device__ inline float gelu_ap(float y) {
    float u = y * (0.7978845608f + 0.0356774081f * y * y);
    float e = __expf(2.0f * u);
    return y - y * __builtin_amdgcn_rcpf(e + 1.0f);
}

#define GLOAD_LDS16(gptr, lptr)                                                     \
    __builtin_amdgcn_global_load_lds(                                               \
        (const __attribute__((address_space(1))) void*)(gptr),                      \
        (__attribute__((address_space(3))) void*)(lptr), 16, 0, 0)

// ---------------------------------------------------------------------------
// Merged prep: x [B,C,N] -> t_b [B,N,C] bf16, plus 4 weight cast+transposes.
__global__ __launch_bounds__(256)
void prep(const float* __restrict__ x, bf16_t* __restrict__ t_b,
          const float* __restrict__ Wqkv, bf16_t* __restrict__ WqkvT,
          const float* __restrict__ Wproj, bf16_t* __restrict__ WprojT,
          const float* __restrict__ Wfc1, bf16_t* __restrict__ Wfc1T,
          const float* __restrict__ Wfc2, bf16_t* __restrict__ Wfc2T) {
    __shared__ float tile[32][33];
    int id = blockIdx.x;
    int tx = threadIdx.x, ty = threadIdx.y;

    const float* src;
    bf16_t* dst;
    int K, N, k0, n0;

    if (id < 8192) {               // transpose x -> t_b (per batch b)
        int b = id >> 10, rem = id & 1023;
        int nn = (rem & 127) * 32, cc = (rem >> 7) * 32;
#pragma unroll
        for (int i = ty; i < 32; i += 8)
            tile[i][tx] = x[(size_t)b * C_ * N_ + (size_t)(cc + i) * N_ + nn + tx];
        __syncthreads();
#pragma unroll
        for (int i = ty; i < 32; i += 8)
            t_b[(size_t)b * N_ * C_ + (size_t)(nn + i) * C_ + cc + tx] = f2b(tile[tx][i]);
        return;
    } else if (id < 8384) {        // Wqkv [256,768] -> [768,256]
        int idw = id - 8192; K = C_; N = 768;
        n0 = (idw % 24) * 32; k0 = (idw / 24) * 32;
        src = Wqkv; dst = WqkvT;
    } else if (id < 8448) {        // Wproj [256,256]
        int idw = id - 8384; K = C_; N = C_;
        n0 = (idw & 7) * 32; k0 = (idw >> 3) * 32;
        src = Wproj; dst = WprojT;
    } else if (id < 8960) {        // Wfc1 [256,2048] -> [2048,256]
        int idw = id - 8448; K = C_; N = CM_;
        n0 = (idw & 63) * 32; k0 = (idw >> 6) * 32;
        src = Wfc1; dst = Wfc1T;
    } else {                       // Wfc2 [2048,256] -> [256,2048]
        int idw = id - 8960; K = CM_; N = C_;
        n0 = (idw & 7) * 32; k0 = (idw >> 3) * 32;
        src = Wfc2; dst = Wfc2T;
    }
#pragma unroll
    for (int i = ty; i < 32; i += 8)
        tile[i][tx] = src[(size_t)(k0 + i) * N + n0 + tx];
    __syncthreads();
#pragma unroll
    for (int i = ty; i < 32; i += 8)
        dst[(size_t)(n0 + i) * K + k0 + tx] = f2b(tile[tx][i]);
}

// ---------------------------------------------------------------------------
// Swapped-operand bf16 MFMA GEMM (qkv / proj): out[m,ch] = Act[m,:].Wt[ch,:]+bias.
// 128x128 tile, BK=64, dbuf, 4 waves. EPI 4: plain; EPI 1: repbn1.
template <int EPI>
__global__ __launch_bounds__(256)
void gemm_swp(const bf16_t* __restrict__ Wt, const bf16_t* __restrict__ Act,
              const float* __restrict__ bias, bf16_t* __restrict__ Cb,
              int M, int N, int K,
              const bf16_t* __restrict__ tres_b,
              const float* __restrict__ g, const float* __restrict__ bb,
              const float* __restrict__ mm, const float* __restrict__ vv,
              const float* __restrict__ alpha) {
    __shared__ bf16x8 ldsv[4096];          // 64 KB: 2 bufs x (W 16KB | Act 16KB)
    char* lds = (char*)ldsv;

    int tid  = threadIdx.x;
    int lane = tid & 63;
    int w    = tid >> 6;
    int wi   = w >> 1, wj = w & 1;

    int nwg = gridDim.x * gridDim.y;
    int bid = blockIdx.y * gridDim.x + blockIdx.x;
    int swz = (bid & 7) * (nwg >> 3) + (bid >> 3);
    int bx = swz % gridDim.x, by = swz / gridDim.x;
    int bch = bx * 128, bm = by * 128;

    int rowl = lane & 15, kq = lane >> 4;

#define STAGE_SWP(k0, p)                                                             \
    {                                                                                \
        _Pragma("unroll")                                                            \
        for (int j = 0; j < 4; ++j) {                                                \
            int jj = w * 4 + j;                                                      \
            int msub = jj >> 1, kh = jj & 1;                                         \
            const bf16_t* gw = Wt + ((size_t)(bch + msub * 16 + rowl) * K + (k0) +   \
                                     kh * 32 + kq * 8);                              \
            GLOAD_LDS16(gw, lds + (p) * 32768 + jj * 1024);                          \
            const bf16_t* ga = Act + ((size_t)(bm + msub * 16 + rowl) * K + (k0) +   \
                                      kh * 32 + kq * 8);                             \
            GLOAD_LDS16(ga, lds + (p) * 32768 + 16384 + jj * 1024);                  \
        }                                                                            \
    }

    f32x4 acc[4][4] = {};
    int T = K >> 6;

    STAGE_SWP(0, 0);
    __syncthreads();

    for (int t = 0; t < T; ++t) {
        int p = t & 1;
        if (t + 1 < T) STAGE_SWP((t + 1) << 6, p ^ 1);
#pragma unroll
        for (int ks = 0; ks < 2; ++ks) {
            bf16x8 wf[4], af[4];
#pragma unroll
            for (int i = 0; i < 4; ++i) wf[i] = ldsv[p * 2048 + ((wi * 4 + i) * 2 + ks) * 64 + lane];
#pragma unroll
            for (int j = 0; j < 4; ++j) af[j] = ldsv[p * 2048 + 1024 + ((wj * 4 + j) * 2 + ks) * 64 + lane];
#pragma unroll
            for (int i = 0; i < 4; ++i)
#pragma unroll
                for (int j = 0; j < 4; ++j)
                    acc[i][j] = __builtin_amdgcn_mfma_f32_16x16x32_bf16(wf[i], af[j], acc[i][j], 0, 0, 0);
        }
        if (t + 1 < T) __syncthreads();
    }

    float alpha_v = (EPI == 1) ? alpha[0] : 0.f;
#pragma unroll
    for (int i = 0; i < 4; ++i) {
        int ch = bch + wi * 64 + i * 16 + (lane >> 4) * 4;
        f32x4 b4 = *(const f32x4*)(bias + ch);
        f32x4 rs4, B4, m4;
        if (EPI == 1) {
            f32x4 g4 = *(const f32x4*)(g + ch);
            f32x4 v4 = *(const f32x4*)(vv + ch);
            B4 = *(const f32x4*)(bb + ch);
            m4 = *(const f32x4*)(mm + ch);
#pragma unroll
            for (int r = 0; r < 4; ++r) rs4[r] = rsqrtf(v4[r] + EPS_) * g4[r];
        }
#pragma unroll
        for (int j = 0; j < 4; ++j) {
            int m = bm + wj * 64 + j * 16 + (lane & 15);
            f32x4 a = acc[i][j];
            bf16_t ob[4];
            if (EPI == 4) {
#pragma unroll
                for (int r = 0; r < 4; ++r) ob[r] = f2b(a[r] + b4[r]);
            } else {  // EPI 1
                bf16x4 t4 = *(const bf16x4*)(tres_b + (size_t)m * N + ch);
#pragma unroll
                for (int r = 0; r < 4; ++r) {
                    float z = b2f(t4[r]) + a[r] + b4[r];
                    ob[r] = f2b((z - m4[r]) * rs4[r] + B4[r] + alpha_v * z);
                }
            }
            *(bf16x4*)(Cb + (size_t)m * N + ch) = *(bf16x4*)ob;
        }
    }
}

// ---------------------------------------------------------------------------
// Fused FFN v3: out = repbn2(t + gelu(t@W1+b1)@W2 + b2) -> [B,C,N] f32.
// Per block: 64-row m-panel, 512 threads (8 waves), LDS 48KB (A 32K + hidden 16K)
// -> 2 blocks/CU, grid = 512 = all co-resident. 16 hidden-chunks of 128:
//   fc1 (swapped: W1 h-rows x act) -> gelu -> hidden chunk in LDS (frag-linear)
//   fc2 (hidden m-frags x W2 ch-frags) accumulates into regs; W1/W2 from L2.
__global__ __launch_bounds__(512, 2)
void ffn_fused(const bf16_t* __restrict__ Act, const bf16_t* __restrict__ W1t,
               const bf16_t* __restrict__ W2t,
               const float* __restrict__ bfc1, const float* __restrict__ bfc2,
               const float* __restrict__ g, const float* __restrict__ bb,
               const float* __restrict__ mm, const float* __restrict__ vv,
               const float* __restrict__ alpha, float* __restrict__ out) {
    __shared__ char lds[49152];
    bf16x8* ldsA = (bf16x8*)lds;            // A panel: 32 frags x 64 lanes
    bf16x8* ldsH = (bf16x8*)(lds + 32768);  // hidden chunk: 16 frags x 64 lanes

    const int tid = threadIdx.x;
    const int lane = tid & 63;
    const int w = tid >> 6;          // 0..7
    const int l15 = lane & 15;
    const int kq = lane >> 4;        // 0..3
    const int m0 = blockIdx.x * 64;

    // ---- stage A panel 64x256 (frag-linear)
#pragma unroll
    for (int j = 0; j < 4; ++j) {
        int jj = w * 4 + j;
        int mblk = jj >> 3, ks = jj & 7;
        const bf16_t* src = Act + (size_t)(m0 + mblk * 16 + l15) * 256 + ks * 32 + kq * 8;
        GLOAD_LDS16(src, lds + jj * 1024);
    }
    __syncthreads();

    f32x4 acc2[2][4] = {};

    const int hrow = w * 16 + l15;                         // W1 row within chunk
    const int ks2w = w >> 1;                               // hidden write frag ks2
    const int lane2 = l15 + (((2 * w + (kq >> 1)) & 3) << 4);
    const int hwoff = (kq & 1) << 3;                       // byte 0 / 8
    const int chb = w * 32;

    for (int c = 0; c < 16; ++c) {
        // ---- fc1: 16h x 64m per wave (swapped)
        bf16x8 w1f[8];
#pragma unroll
        for (int ks = 0; ks < 8; ++ks)
            w1f[ks] = *(const bf16x8*)(W1t + (size_t)(c * 128 + hrow) * 256 + ks * 32 + kq * 8);
        f32x4 acc1[4] = {};
#pragma unroll
        for (int ks = 0; ks < 8; ++ks)
#pragma unroll
            for (int mblk = 0; mblk < 4; ++mblk)
                acc1[mblk] = __builtin_amdgcn_mfma_f32_16x16x32_bf16(
                    w1f[ks], ldsA[(mblk * 8 + ks) * 64 + lane], acc1[mblk], 0, 0, 0);

        // ---- bias + gelu + pack -> hidden LDS (matches fc2 A-frag layout)
        f32x4 b1 = *(const f32x4*)(bfc1 + c * 128 + w * 16 + kq * 4);
#pragma unroll
        for (int mblk = 0; mblk < 4; ++mblk) {
            unsigned lo = pk2(gelu_ap(acc1[mblk][0] + b1[0]), gelu_ap(acc1[mblk][1] + b1[1]));
            unsigned hi = pk2(gelu_ap(acc1[mblk][2] + b1[2]), gelu_ap(acc1[mblk][3] + b1[3]));
            char* dst = lds + 32768 + (size_t)((mblk * 4 + ks2w) * 64 + lane2) * 16 + hwoff;
            *(unsigned*)dst = lo;
            *(unsigned*)(dst + 4) = hi;
        }
        __syncthreads();

        // ---- fc2 partial: 64m x 32ch per wave (non-swapped: m-frags x ch-frags)
        bf16x8 w2f[2][4];
#pragma unroll
        for (int cf = 0; cf < 2; ++cf)
#pragma unroll
            for (int ks2 = 0; ks2 < 4; ++ks2)
                w2f[cf][ks2] = *(const bf16x8*)(W2t + (size_t)(chb + cf * 16 + l15) * 2048 + c * 128 + ks2 * 32 + kq * 8);
#pragma unroll
        for (int mblk = 0; mblk < 4; ++mblk)
#pragma unroll
            for (int ks2 = 0; ks2 < 4; ++ks2) {
                bf16x8 hf = ldsH[(mblk * 4 + ks2) * 64 + lane];
                acc2[0][mblk] = __builtin_amdgcn_mfma_f32_16x16x32_bf16(hf, w2f[0][ks2], acc2[0][mblk], 0, 0, 0);
                acc2[1][mblk] = __builtin_amdgcn_mfma_f32_16x16x32_bf16(hf, w2f[1][ks2], acc2[1][mblk], 0, 0, 0);
            }
        __syncthreads();
    }

    // ---- epilogue: repbn2 + transpose to [B,C,N], native f32x4 stores
    float alpha_v = alpha[0];
#pragma unroll
    for (int cf = 0; cf < 2; ++cf) {
        int ch = chb + cf * 16 + l15;
        float b2v = bfc2[ch];
        float rs = rsqrtf(vv[ch] + EPS_) * g[ch];
        float bbv = bb[ch], mv = mm[ch];
#pragma unroll
        for (int mblk = 0; mblk < 4; ++mblk) {
            int mbase = m0 + mblk * 16 + kq * 4;
            f32x4 o4;
#pragma unroll
            for (int r = 0; r < 4; ++r) {
                float z = b2f(Act[(size_t)(mbase + r) * 256 + ch]) + acc2[cf][mblk][r] + b2v;
                o4[r] = (z - mv) * rs + bbv + alpha_v * z;
            }
            int bi = mbase >> 12, ni = mbase & (N_ - 1);
            *(f32x4*)(out + ((size_t)bi * C_ + ch) * N_ + ni) = o4;
        }
    }
}

// ---------------------------------------------------------------------------
// Transpose [B,C,N] -> [B,N,C] bf16 (conv output path)
__global__ void transpose_b(const bf16_t* __restrict__ in_, bf16_t* __restrict__ outb) {
    __shared__ float tile[32][33];
    int b  = blockIdx.z;
    int n0 = blockIdx.x * 32;
    int c0 = blockIdx.y * 32;
    int tx = threadIdx.x, ty = threadIdx.y;
#pragma unroll
    for (int i = ty; i < 32; i += 8)
        tile[i][tx] = b2f(in_[(size_t)b * C_ * N_ + (size_t)(c0 + i) * N_ + n0 + tx]);
    __syncthreads();
#pragma unroll
    for (int i = ty; i < 32; i += 8)
        outb[(size_t)b * N_ * C_ + (size_t)(n0 + i) * C_ + c0 + tx] = f2b(tile[tx][i]);
}

// ---------------------------------------------------------------------------
__global__ void ctx_partial(const bf16_t* __restrict__ qkv, float* __restrict__ ctxp) {
    __shared__ float kb[64][40];
    __shared__ float vb[64][40];
    int seg = blockIdx.x;
    int bh  = blockIdx.y;
    int b = bh >> 3, h = bh & 7;
    int tid = threadIdx.x;
    int d  = tid >> 3;
    int e0 = (tid & 7) * 4;
    int lrow = tid >> 2, lcol = (tid & 3) * 8;
    float acc[4] = {0.f, 0.f, 0.f, 0.f};
    const size_t base = (size_t)b * N_ * 768 + h * 32;
    for (int n0 = seg * 512; n0 < seg * 512 + 512; n0 += 64) {
        size_t ra = base + (size_t)(n0 + lrow) * 768 + lcol;
        bf16x8 kv8 = *(const bf16x8*)(qkv + ra + 256);
        bf16x8 vv8 = *(const bf16x8*)(qkv + ra + 512);
#pragma unroll
        for (int j = 0; j < 8; ++j) {
            kb[lrow][lcol + j] = b2f(kv8[j]);
            vb[lrow][lcol + j] = b2f(vv8[j]);
        }
        __syncthreads();
#pragma unroll
        for (int nl = 0; nl < 64; ++nl) {
            float kv = fmaxf(kb[nl][d], 0.f);
#pragma unroll
            for (int j = 0; j < 4; ++j)
                acc[j] = fmaf(kv, vb[nl][e0 + j], acc[j]);
        }
        __syncthreads();
    }
    float* o = ctxp + ((size_t)seg * 64 + bh) * 1024 + d * 32 + e0;
#pragma unroll
    for (int j = 0; j < 4; ++j) o[j] = acc[j];
}

__global__ void ctx_reduce(const float* __restrict__ ctxp, float* __restrict__ ctx) {
    int idx = blockIdx.x * 256 + threadIdx.x;
    float s = 0.f;
#pragma unroll
    for (int seg = 0; seg < 8; ++seg) s += ctxp[(size_t)seg * 65536 + idx];
    ctx[idx] = s;
}

// ---------------------------------------------------------------------------
__global__ void attn_out(const bf16_t* __restrict__ qkv, const float* __restrict__ ctx,
                         bf16_t* __restrict__ img) {
    __shared__ float qb[64][33];
    __shared__ float cs[32][32];
    int n0 = blockIdx.x * 64;
    int bh = blockIdx.y;
    int b = bh >> 3, h = bh & 7;
    int tid = threadIdx.x;
    const float scale = 0.17677669529663687f;
    {
        float4 vv = ((const float4*)(ctx + (size_t)bh * 1024))[tid];
        ((float4*)&cs[0][0])[tid] = vv;
    }
    const size_t base = (size_t)b * N_ * 768 + h * 32;
    int lrow = tid >> 2, lcol = (tid & 3) * 8;
    {
        bf16x8 q8 = *(const bf16x8*)(qkv + base + (size_t)(n0 + lrow) * 768 + lcol);
#pragma unroll
        for (int j = 0; j < 8; ++j)
            qb[lrow][lcol + j] = fmaxf(b2f(q8[j]), 0.f) * scale;
    }
    __syncthreads();
    int nl = tid & 63, ebase = tid >> 6;
    bf16_t* outp = img + ((size_t)b * C_ + h * 32) * N_ + n0 + nl;
#pragma unroll
    for (int p = 0; p < 8; ++p) {
        int e = ebase + p * 4;
        float s = 0.f;
#pragma unroll
        for (int dd = 0; dd < 32; ++dd)
            s = fmaf(qb[nl][dd], cs[dd][e], s);
        outp[(size_t)e * N_] = f2b(s);
    }
}

// ---------------------------------------------------------------------------
__global__ __launch_bounds__(256)
void dwconv3x3(const bf16_t* __restrict__ img, const float* __restrict__ w,
               const float* __restrict__ bias, bf16_t* __restrict__ out) {
    __shared__ float sp[64][65];
    int bc = blockIdx.x;
    int c  = bc & 255;
    int tid = threadIdx.x;
    const bf16_t* ip = img + (size_t)bc * N_;
#pragma unroll
    for (int l = 0; l < 2; ++l) {
        int flat = (tid + l * 256) * 8;
        int row = flat >> 6, col = flat & 63;
        bf16x8 v8 = *(const bf16x8*)(ip + flat);
#pragma unroll
        for (int j = 0; j < 8; ++j) sp[row][col + j] = b2f(v8[j]);
    }
    float wv[9];
#pragma unroll
    for (int j = 0; j < 9; ++j) wv[j] = w[c * 9 + j];
    float bv = bias[c];
    __syncthreads();

    int y = tid >> 2, x0 = (tid & 3) * 16;
    float o[16];
#pragma unroll
    for (int i = 0; i < 16; ++i) o[i] = bv;
#pragma unroll
    for (int dy = -1; dy <= 1; ++dy) {
        int yy = y + dy;
        if (yy < 0 || yy > 63) continue;
#pragma unroll
        for (int dx = -1; dx <= 1; ++dx) {
            float wgt = wv[(dy + 1) * 3 + dx + 1];
#pragma unroll
            for (int i = 0; i < 16; ++i) {
                int xx = x0 + i + dx;
                float val = (xx < 0 || xx > 63) ? 0.f : sp[yy][xx];
                o[i] = fmaf(wgt, val, o[i]);
            }
        }
    }
    bf16_t ob[16];
#pragma unroll
    for (int i = 0; i < 16; ++i) ob[i] = f2b(o[i]);
    *(bf16x8*)(out + (size_t)bc * N_ + y * 64 + x0)     = *(bf16x8*)&ob[0];
    *(bf16x8*)(out + (size_t)bc * N_ + y * 64 + x0 + 8) = *(bf16x8*)&ob[8];
}

// ---------------------------------------------------------------------------
extern "C" void kernel_launch(void* const* d_in, const int* in_sizes, int n_in,
                              void* d_out, int out_size, void* d_ws, size_t ws_size,
                              hipStream_t stream) {
    const float* x     = (const float*)d_in[0];
    const float* Wqkv  = (const float*)d_in[1];
    const float* bqkv  = (const float*)d_in[2];
    const float* dw_w  = (const float*)d_in[3];
    const float* dw_b  = (const float*)d_in[4];
    const float* Wproj = (const float*)d_in[5];
    const float* bproj = (const float*)d_in[6];
    const float* bn1_g = (const float*)d_in[7];
    const float* bn1_b = (const float*)d_in[8];
    const float* bn1_m = (const float*)d_in[9];
    const float* bn1_v = (const float*)d_in[10];
    const float* alpha1= (const float*)d_in[11];
    const float* Wfc1  = (const float*)d_in[12];
    const float* bfc1  = (const float*)d_in[13];
    const float* Wfc2  = (const float*)d_in[14];
    const float* bfc2  = (const float*)d_in[15];
    const float* bn2_g = (const float*)d_in[16];
    const float* bn2_b = (const float*)d_in[17];
    const float* bn2_m = (const float*)d_in[18];
    const float* bn2_v = (const float*)d_in[19];
    const float* alpha2= (const float*)d_in[20];
    float* out = (float*)d_out;

    char* ws = (char*)d_ws;
    bf16_t* t_b2    = (bf16_t*)(ws);
    bf16_t* WqkvT   = (bf16_t*)(ws + 16777216);
    bf16_t* WprojT  = (bf16_t*)(ws + 17170432);
    bf16_t* Wfc1T   = (bf16_t*)(ws + 17301504);
    bf16_t* Wfc2T   = (bf16_t*)(ws + 18350080);
    float*  ctxp    = (float*)(ws + 19398656);
    float*  ctx     = (float*)(ws + 21495808);
    bf16_t* t_b     = (bf16_t*)(ws + 21757952);
    bf16_t* qkv_b   = (bf16_t*)(ws + 38535168);
    bf16_t* img_b   = (bf16_t*)(ws + 88866816);
    bf16_t* conv_b  = (bf16_t*)(ws + 105644032);
    bf16_t* convT_b = (bf16_t*)(ws + 122421248);

    // ph1: merged prep (transpose x + all 4 weight casts)
    prep<<<9472, dim3(32, 8), 0, stream>>>(x, t_b, Wqkv, WqkvT, Wproj, WprojT,
                                           Wfc1, Wfc1T, Wfc2, Wfc2T);

    // ph2: qkv_b = bf16(t @ Wqkv + bqkv)
    gemm_swp<4><<<dim3(768 / 128, M_ / 128), 256, 0, stream>>>(
        WqkvT, t_b, bqkv, qkv_b, M_, 768, C_,
        nullptr, nullptr, nullptr, nullptr, nullptr, nullptr);

    // ph3: ctx = relu(k)^T v
    ctx_partial<<<dim3(8, B_ * NH_), 256, 0, stream>>>(qkv_b, ctxp);
    ctx_reduce<<<256, 256, 0, stream>>>(ctxp, ctx);

    // ph4: img_b = (relu(q)*scale) @ ctx   [B,C,N] bf16
    attn_out<<<dim3(N_ / 64, B_ * NH_), 256, 0, stream>>>(qkv_b, ctx, img_b);

    // ph5: depthwise conv (bf16 -> bf16)
    dwconv3x3<<<B_ * C_, 256, 0, stream>>>(img_b, dw_w, dw_b, conv_b);

    // ph6: conv_b -> convT_b (bf16 [B,N,C])
    transpose_b<<<dim3(N_ / 32, C_ / 32, B_), dim3(32, 8), 0, stream>>>(conv_b, convT_b);

    // ph7: t_b2 = repbn1(t_b + convT @ Wproj + bproj)
    gemm_swp<1><<<dim3(C_ / 128, M_ / 128), 256, 0, stream>>>(
        WprojT, convT_b, bproj, t_b2, M_, C_, C_,
        t_b, bn1_g, bn1_b, bn1_m, bn1_v, alpha1);

    // ph8: fused FFN v3 (fc1+gelu+fc2+repbn2+transpose-out, no hidden tensor)
    ffn_fused<<<M_ / 64, 512, 0, stream>>>(
        t_b2, Wfc1T, Wfc2T, bfc1, bfc2,
        bn2_g, bn2_b, bn2_m, bn2_v, alpha2, out);
}

// Round 11
// 296.603 us; speedup vs baseline: 1.4927x; 1.0239x over previous
//
#include <hip/hip_runtime.h>
#include <hip/hip_bf16.h>
#include <math.h>

// Problem constants
constexpr int B_ = 8, C_ = 256, H_ = 64, W_ = 64;
constexpr int N_ = H_ * W_;          // 4096
constexpr int NH_ = 8;
constexpr int CM_ = 2048;
constexpr int M_ = B_ * N_;          // 32768
constexpr float EPS_ = 1e-5f;

typedef __bf16 bf16_t;
typedef bf16_t bf16x4 __attribute__((ext_vector_type(4)));
typedef bf16_t bf16x8 __attribute__((ext_vector_type(8)));
typedef float f32x4 __attribute__((ext_vector_type(4)));

__device__ inline bf16_t f2b(float f) {
    __hip_bfloat16 h = __float2bfloat16(f);
    return *reinterpret_cast<bf16_t*>(&h);
}
__device__ inline float b2f(bf16_t b) {
    unsigned short u = *reinterpret_cast<unsigned short*>(&b);
    unsigned int x = (unsigned int)u << 16;
    return *reinterpret_cast<float*>(&x);
}
__device__ inline unsigned pk2(float lo, float hi) {
    bf16_t l = f2b(lo), h = f2b(hi);
    unsigned short ls = *reinterpret_cast<unsigned short*>(&l);
    unsigned short hs = *reinterpret_cast<unsigned short*>(&h);
    return ((unsigned)hs << 16) | (unsigned)ls;
}
__device__ inline float gelu_ap(float y) {
    float u = y * (0.7978845608f + 0.0356774081f * y * y);
    float e = __expf(2.0f * u);
    return y - y * __builtin_amdgcn_rcpf(e + 1.0f);
}

#define GLOAD_LDS16(gptr, lptr)                                                     \
    __builtin_amdgcn_global_load_lds(                                               \
        (const __attribute__((address_space(1))) void*)(gptr),                      \
        (__attribute__((address_space(3))) void*)(lptr), 16, 0, 0)

// ---------------------------------------------------------------------------
// Merged prep: x [B,C,N] -> t_b [B,N,C] bf16, plus 4 weight cast+transposes.
__global__ __launch_bounds__(256)
void prep(const float* __restrict__ x, bf16_t* __restrict__ t_b,
          const float* __restrict__ Wqkv, bf16_t* __restrict__ WqkvT,
          const float* __restrict__ Wproj, bf16_t* __restrict__ WprojT,
          const float* __restrict__ Wfc1, bf16_t* __restrict__ Wfc1T,
          const float* __restrict__ Wfc2, bf16_t* __restrict__ Wfc2T) {
    __shared__ float tile[32][33];
    int id = blockIdx.x;
    int tx = threadIdx.x, ty = threadIdx.y;

    const float* src;
    bf16_t* dst;
    int K, N, k0, n0;

    if (id < 8192) {               // transpose x -> t_b (per batch b)
        int b = id >> 10, rem = id & 1023;
        int nn = (rem & 127) * 32, cc = (rem >> 7) * 32;
#pragma unroll
        for (int i = ty; i < 32; i += 8)
            tile[i][tx] = x[(size_t)b * C_ * N_ + (size_t)(cc + i) * N_ + nn + tx];
        __syncthreads();
#pragma unroll
        for (int i = ty; i < 32; i += 8)
            t_b[(size_t)b * N_ * C_ + (size_t)(nn + i) * C_ + cc + tx] = f2b(tile[tx][i]);
        return;
    } else if (id < 8384) {        // Wqkv [256,768] -> [768,256]
        int idw = id - 8192; K = C_; N = 768;
        n0 = (idw % 24) * 32; k0 = (idw / 24) * 32;
        src = Wqkv; dst = WqkvT;
    } else if (id < 8448) {        // Wproj [256,256]
        int idw = id - 8384; K = C_; N = C_;
        n0 = (idw & 7) * 32; k0 = (idw >> 3) * 32;
        src = Wproj; dst = WprojT;
    } else if (id < 8960) {        // Wfc1 [256,2048] -> [2048,256]
        int idw = id - 8448; K = C_; N = CM_;
        n0 = (idw & 63) * 32; k0 = (idw >> 6) * 32;
        src = Wfc1; dst = Wfc1T;
    } else {                       // Wfc2 [2048,256] -> [256,2048]
        int idw = id - 8960; K = CM_; N = C_;
        n0 = (idw & 7) * 32; k0 = (idw >> 3) * 32;
        src = Wfc2; dst = Wfc2T;
    }
#pragma unroll
    for (int i = ty; i < 32; i += 8)
        tile[i][tx] = src[(size_t)(k0 + i) * N + n0 + tx];
    __syncthreads();
#pragma unroll
    for (int i = ty; i < 32; i += 8)
        dst[(size_t)(n0 + i) * K + k0 + tx] = f2b(tile[tx][i]);
}

// ---------------------------------------------------------------------------
// Swapped-operand bf16 MFMA GEMM (qkv / proj): out[m,ch] = Act[m,:].Wt[ch,:]+bias.
// 128x128 tile, BK=64, single-buffer 32KB LDS, 4 blocks/CU. EPI 4 / EPI 1.
template <int EPI>
__global__ __launch_bounds__(256, 4)
void gemm_swp(const bf16_t* __restrict__ Wt, const bf16_t* __restrict__ Act,
              const float* __restrict__ bias, bf16_t* __restrict__ Cb,
              int M, int N, int K,
              const bf16_t* __restrict__ tres_b,
              const float* __restrict__ g, const float* __restrict__ bb,
              const float* __restrict__ mm, const float* __restrict__ vv,
              const float* __restrict__ alpha) {
    __shared__ bf16x8 ldsv[2048];          // 32 KB: W [0,1024), Act [1024,2048)
    char* lds = (char*)ldsv;

    int tid  = threadIdx.x;
    int lane = tid & 63;
    int w    = tid >> 6;
    int wi   = w >> 1, wj = w & 1;

    int nwg = gridDim.x * gridDim.y;
    int bid = blockIdx.y * gridDim.x + blockIdx.x;
    int swz = (bid & 7) * (nwg >> 3) + (bid >> 3);
    int bx = swz % gridDim.x, by = swz / gridDim.x;
    int bch = bx * 128, bm = by * 128;

    int rowl = lane & 15, kq = lane >> 4;

    f32x4 acc[4][4] = {};

    for (int k0 = 0; k0 < K; k0 += 64) {
#pragma unroll
        for (int j = 0; j < 4; ++j) {
            int jj = w * 4 + j;
            int msub = jj >> 1, kh = jj & 1;
            const bf16_t* gw = Wt + ((size_t)(bch + msub * 16 + rowl) * K + k0 + kh * 32 + kq * 8);
            GLOAD_LDS16(gw, lds + jj * 1024);
            const bf16_t* ga = Act + ((size_t)(bm + msub * 16 + rowl) * K + k0 + kh * 32 + kq * 8);
            GLOAD_LDS16(ga, lds + 16384 + jj * 1024);
        }
        __syncthreads();
#pragma unroll
        for (int ks = 0; ks < 2; ++ks) {
            bf16x8 wf[4], af[4];
#pragma unroll
            for (int i = 0; i < 4; ++i) wf[i] = ldsv[((wi * 4 + i) * 2 + ks) * 64 + lane];
#pragma unroll
            for (int j = 0; j < 4; ++j) af[j] = ldsv[1024 + ((wj * 4 + j) * 2 + ks) * 64 + lane];
#pragma unroll
            for (int i = 0; i < 4; ++i)
#pragma unroll
                for (int j = 0; j < 4; ++j)
                    acc[i][j] = __builtin_amdgcn_mfma_f32_16x16x32_bf16(wf[i], af[j], acc[i][j], 0, 0, 0);
        }
        __syncthreads();
    }

    float alpha_v = (EPI == 1) ? alpha[0] : 0.f;
#pragma unroll
    for (int i = 0; i < 4; ++i) {
        int ch = bch + wi * 64 + i * 16 + (lane >> 4) * 4;
        f32x4 b4 = *(const f32x4*)(bias + ch);
        f32x4 rs4, B4, m4;
        if (EPI == 1) {
            f32x4 g4 = *(const f32x4*)(g + ch);
            f32x4 v4 = *(const f32x4*)(vv + ch);
            B4 = *(const f32x4*)(bb + ch);
            m4 = *(const f32x4*)(mm + ch);
#pragma unroll
            for (int r = 0; r < 4; ++r) rs4[r] = rsqrtf(v4[r] + EPS_) * g4[r];
        }
#pragma unroll
        for (int j = 0; j < 4; ++j) {
            int m = bm + wj * 64 + j * 16 + (lane & 15);
            f32x4 a = acc[i][j];
            bf16_t ob[4];
            if (EPI == 4) {
#pragma unroll
                for (int r = 0; r < 4; ++r) ob[r] = f2b(a[r] + b4[r]);
            } else {  // EPI 1
                bf16x4 t4 = *(const bf16x4*)(tres_b + (size_t)m * N + ch);
#pragma unroll
                for (int r = 0; r < 4; ++r) {
                    float z = b2f(t4[r]) + a[r] + b4[r];
                    ob[r] = f2b((z - m4[r]) * rs4[r] + B4[r] + alpha_v * z);
                }
            }
            *(bf16x4*)(Cb + (size_t)m * N + ch) = *(bf16x4*)ob;
        }
    }
}

// ---------------------------------------------------------------------------
// Fused FFN v4: out = repbn2(t + gelu(t@W1+b1)@W2 + b2) -> [B,C,N] f32.
// Per block: 64-row m-panel, 512 threads (8 waves), LDS 64KB (A 32K + 2x16K
// hidden double-buffer) -> 2 blocks/CU. 16 hidden-chunks of 128.
// ONE barrier per chunk (dbuf removes the WAR hazard); w1f reloaded into dead
// regs right after consumption; w2f issued before the barrier -> all global
// loads covered by compute before their use.
__global__ __launch_bounds__(512, 4)
void ffn_fused(const bf16_t* __restrict__ Act, const bf16_t* __restrict__ W1t,
               const bf16_t* __restrict__ W2t,
               const float* __restrict__ bfc1, const float* __restrict__ bfc2,
               const float* __restrict__ g, const float* __restrict__ bb,
               const float* __restrict__ mm, const float* __restrict__ vv,
               const float* __restrict__ alpha, float* __restrict__ out) {
    __shared__ char lds[65536];
    bf16x8* ldsA = (bf16x8*)lds;            // A panel: 32 frags x 64 lanes

    const int tid = threadIdx.x;
    const int lane = tid & 63;
    const int w = tid >> 6;          // 0..7
    const int l15 = lane & 15;
    const int kq = lane >> 4;        // 0..3
    const int m0 = blockIdx.x * 64;

    // ---- stage A panel 64x256 (frag-linear)
#pragma unroll
    for (int j = 0; j < 4; ++j) {
        int jj = w * 4 + j;
        int mblk = jj >> 3, ks = jj & 7;
        const bf16_t* src = Act + (size_t)(m0 + mblk * 16 + l15) * 256 + ks * 32 + kq * 8;
        GLOAD_LDS16(src, lds + jj * 1024);
    }
    __syncthreads();

    f32x4 acc2[2][4] = {};

    const int hrow = w * 16 + l15;                         // W1 row within chunk
    const int ks2w = w >> 1;                               // hidden write frag ks2
    const int lane2 = l15 + (((2 * w + (kq >> 1)) & 3) << 4);
    const int hwoff = (kq & 1) << 3;                       // byte 0 / 8
    const int chb = w * 32;

    // ---- prologue: W1 chunk 0 -> regs
    bf16x8 w1f[8];
#pragma unroll
    for (int ks = 0; ks < 8; ++ks)
        w1f[ks] = *(const bf16x8*)(W1t + (size_t)hrow * 256 + ks * 32 + kq * 8);

    for (int c = 0; c < 16; ++c) {
        // ---- fc1: 16h x 64m per wave (swapped)
        f32x4 acc1[4] = {};
#pragma unroll
        for (int ks = 0; ks < 8; ++ks)
#pragma unroll
            for (int mblk = 0; mblk < 4; ++mblk)
                acc1[mblk] = __builtin_amdgcn_mfma_f32_16x16x32_bf16(
                    w1f[ks], ldsA[(mblk * 8 + ks) * 64 + lane], acc1[mblk], 0, 0, 0);

        // ---- reload W1 for next chunk into the now-dead regs
        if (c + 1 < 16) {
#pragma unroll
            for (int ks = 0; ks < 8; ++ks)
                w1f[ks] = *(const bf16x8*)(W1t + (size_t)((c + 1) * 128 + hrow) * 256 + ks * 32 + kq * 8);
        }
        // ---- W2 chunk c -> regs (used after the barrier; covered by gelu+drain)
        bf16x8 w2f[2][4];
#pragma unroll
        for (int cf = 0; cf < 2; ++cf)
#pragma unroll
            for (int ks2 = 0; ks2 < 4; ++ks2)
                w2f[cf][ks2] = *(const bf16x8*)(W2t + (size_t)(chb + cf * 16 + l15) * 2048 + c * 128 + ks2 * 32 + kq * 8);

        // ---- bias + gelu + pack -> hidden buf[c&1] (b64 writes)
        f32x4 b1 = *(const f32x4*)(bfc1 + c * 128 + w * 16 + kq * 4);
        char* hbase = lds + 32768 + (c & 1) * 16384;
#pragma unroll
        for (int mblk = 0; mblk < 4; ++mblk) {
            uint2 u2;
            u2.x = pk2(gelu_ap(acc1[mblk][0] + b1[0]), gelu_ap(acc1[mblk][1] + b1[1]));
            u2.y = pk2(gelu_ap(acc1[mblk][2] + b1[2]), gelu_ap(acc1[mblk][3] + b1[3]));
            *(uint2*)(hbase + (size_t)((mblk * 4 + ks2w) * 64 + lane2) * 16 + hwoff) = u2;
        }
        __syncthreads();   // single barrier per chunk (dbuf removes WAR hazard)

        // ---- fc2 partial: 64m x 32ch per wave
        bf16x8* ldsH = (bf16x8*)(lds + 32768 + (c & 1) * 16384);
#pragma unroll
        for (int mblk = 0; mblk < 4; ++mblk)
#pragma unroll
            for (int ks2 = 0; ks2 < 4; ++ks2) {
                bf16x8 hf = ldsH[(mblk * 4 + ks2) * 64 + lane];
                acc2[0][mblk] = __builtin_amdgcn_mfma_f32_16x16x32_bf16(hf, w2f[0][ks2], acc2[0][mblk], 0, 0, 0);
                acc2[1][mblk] = __builtin_amdgcn_mfma_f32_16x16x32_bf16(hf, w2f[1][ks2], acc2[1][mblk], 0, 0, 0);
            }
    }

    // ---- epilogue: repbn2 + transpose to [B,C,N], native f32x4 stores
    float alpha_v = alpha[0];
#pragma unroll
    for (int cf = 0; cf < 2; ++cf) {
        int ch = chb + cf * 16 + l15;
        float b2v = bfc2[ch];
        float rs = rsqrtf(vv[ch] + EPS_) * g[ch];
        float bbv = bb[ch], mv = mm[ch];
#pragma unroll
        for (int mblk = 0; mblk < 4; ++mblk) {
            int mbase = m0 + mblk * 16 + kq * 4;
            f32x4 o4;
#pragma unroll
            for (int r = 0; r < 4; ++r) {
                float z = b2f(Act[(size_t)(mbase + r) * 256 + ch]) + acc2[cf][mblk][r] + b2v;
                o4[r] = (z - mv) * rs + bbv + alpha_v * z;
            }
            int bi = mbase >> 12, ni = mbase & (N_ - 1);
            *(f32x4*)(out + ((size_t)bi * C_ + ch) * N_ + ni) = o4;
        }
    }
}

// ---------------------------------------------------------------------------
// Transpose [B,C,N] -> [B,N,C] bf16 (conv output path)
__global__ void transpose_b(const bf16_t* __restrict__ in_, bf16_t* __restrict__ outb) {
    __shared__ float tile[32][33];
    int b  = blockIdx.z;
    int n0 = blockIdx.x * 32;
    int c0 = blockIdx.y * 32;
    int tx = threadIdx.x, ty = threadIdx.y;
#pragma unroll
    for (int i = ty; i < 32; i += 8)
        tile[i][tx] = b2f(in_[(size_t)b * C_ * N_ + (size_t)(c0 + i) * N_ + n0 + tx]);
    __syncthreads();
#pragma unroll
    for (int i = ty; i < 32; i += 8)
        outb[(size_t)b * N_ * C_ + (size_t)(n0 + i) * C_ + c0 + tx] = f2b(tile[tx][i]);
}

// ---------------------------------------------------------------------------
__global__ void ctx_partial(const bf16_t* __restrict__ qkv, float* __restrict__ ctxp) {
    __shared__ float kb[64][40];
    __shared__ float vb[64][40];
    int seg = blockIdx.x;
    int bh  = blockIdx.y;
    int b = bh >> 3, h = bh & 7;
    int tid = threadIdx.x;
    int d  = tid >> 3;
    int e0 = (tid & 7) * 4;
    int lrow = tid >> 2, lcol = (tid & 3) * 8;
    float acc[4] = {0.f, 0.f, 0.f, 0.f};
    const size_t base = (size_t)b * N_ * 768 + h * 32;
    for (int n0 = seg * 512; n0 < seg * 512 + 512; n0 += 64) {
        size_t ra = base + (size_t)(n0 + lrow) * 768 + lcol;
        bf16x8 kv8 = *(const bf16x8*)(qkv + ra + 256);
        bf16x8 vv8 = *(const bf16x8*)(qkv + ra + 512);
#pragma unroll
        for (int j = 0; j < 8; ++j) {
            kb[lrow][lcol + j] = b2f(kv8[j]);
            vb[lrow][lcol + j] = b2f(vv8[j]);
        }
        __syncthreads();
#pragma unroll
        for (int nl = 0; nl < 64; ++nl) {
            float kv = fmaxf(kb[nl][d], 0.f);
#pragma unroll
            for (int j = 0; j < 4; ++j)
                acc[j] = fmaf(kv, vb[nl][e0 + j], acc[j]);
        }
        __syncthreads();
    }
    float* o = ctxp + ((size_t)seg * 64 + bh) * 1024 + d * 32 + e0;
#pragma unroll
    for (int j = 0; j < 4; ++j) o[j] = acc[j];
}

__global__ void ctx_reduce(const float* __restrict__ ctxp, float* __restrict__ ctx) {
    int idx = blockIdx.x * 256 + threadIdx.x;
    float s = 0.f;
#pragma unroll
    for (int seg = 0; seg < 8; ++seg) s += ctxp[(size_t)seg * 65536 + idx];
    ctx[idx] = s;
}

// ---------------------------------------------------------------------------
__global__ void attn_out(const bf16_t* __restrict__ qkv, const float* __restrict__ ctx,
                         bf16_t* __restrict__ img) {
    __shared__ float qb[64][33];
    __shared__ float cs[32][32];
    int n0 = blockIdx.x * 64;
    int bh = blockIdx.y;
    int b = bh >> 3, h = bh & 7;
    int tid = threadIdx.x;
    const float scale = 0.17677669529663687f;
    {
        float4 vv = ((const float4*)(ctx + (size_t)bh * 1024))[tid];
        ((float4*)&cs[0][0])[tid] = vv;
    }
    const size_t base = (size_t)b * N_ * 768 + h * 32;
    int lrow = tid >> 2, lcol = (tid & 3) * 8;
    {
        bf16x8 q8 = *(const bf16x8*)(qkv + base + (size_t)(n0 + lrow) * 768 + lcol);
#pragma unroll
        for (int j = 0; j < 8; ++j)
            qb[lrow][lcol + j] = fmaxf(b2f(q8[j]), 0.f) * scale;
    }
    __syncthreads();
    int nl = tid & 63, ebase = tid >> 6;
    bf16_t* outp = img + ((size_t)b * C_ + h * 32) * N_ + n0 + nl;
#pragma unroll
    for (int p = 0; p < 8; ++p) {
        int e = ebase + p * 4;
        float s = 0.f;
#pragma unroll
        for (int dd = 0; dd < 32; ++dd)
            s = fmaf(qb[nl][dd], cs[dd][e], s);
        outp[(size_t)e * N_] = f2b(s);
    }
}

// ---------------------------------------------------------------------------
__global__ __launch_bounds__(256)
void dwconv3x3(const bf16_t* __restrict__ img, const float* __restrict__ w,
               const float* __restrict__ bias, bf16_t* __restrict__ out) {
    __shared__ float sp[64][65];
    int bc = blockIdx.x;
    int c  = bc & 255;
    int tid = threadIdx.x;
    const bf16_t* ip = img + (size_t)bc * N_;
#pragma unroll
    for (int l = 0; l < 2; ++l) {
        int flat = (tid + l * 256) * 8;
        int row = flat >> 6, col = flat & 63;
        bf16x8 v8 = *(const bf16x8*)(ip + flat);
#pragma unroll
        for (int j = 0; j < 8; ++j) sp[row][col + j] = b2f(v8[j]);
    }
    float wv[9];
#pragma unroll
    for (int j = 0; j < 9; ++j) wv[j] = w[c * 9 + j];
    float bv = bias[c];
    __syncthreads();

    int y = tid >> 2, x0 = (tid & 3) * 16;
    float o[16];
#pragma unroll
    for (int i = 0; i < 16; ++i) o[i] = bv;
#pragma unroll
    for (int dy = -1; dy <= 1; ++dy) {
        int yy = y + dy;
        if (yy < 0 || yy > 63) continue;
#pragma unroll
        for (int dx = -1; dx <= 1; ++dx) {
            float wgt = wv[(dy + 1) * 3 + dx + 1];
#pragma unroll
            for (int i = 0; i < 16; ++i) {
                int xx = x0 + i + dx;
                float val = (xx < 0 || xx > 63) ? 0.f : sp[yy][xx];
                o[i] = fmaf(wgt, val, o[i]);
            }
        }
    }
    bf16_t ob[16];
#pragma unroll
    for (int i = 0; i < 16; ++i) ob[i] = f2b(o[i]);
    *(bf16x8*)(out + (size_t)bc * N_ + y * 64 + x0)     = *(bf16x8*)&ob[0];
    *(bf16x8*)(out + (size_t)bc * N_ + y * 64 + x0 + 8) = *(bf16x8*)&ob[8];
}

// ---------------------------------------------------------------------------
extern "C" void kernel_launch(void* const* d_in, const int* in_sizes, int n_in,
                              void* d_out, int out_size, void* d_ws, size_t ws_size,
                              hipStream_t stream) {
    const float* x     = (const float*)d_in[0];
    const float* Wqkv  = (const float*)d_in[1];
    const float* bqkv  = (const float*)d_in[2];
    const float* dw_w  = (const float*)d_in[3];
    const float* dw_b  = (const float*)d_in[4];
    const float* Wproj = (const float*)d_in[5];
    const float* bproj = (const float*)d_in[6];
    const float* bn1_g = (const float*)d_in[7];
    const float* bn1_b = (const float*)d_in[8];
    const float* bn1_m = (const float*)d_in[9];
    const float* bn1_v = (const float*)d_in[10];
    const float* alpha1= (const float*)d_in[11];
    const float* Wfc1  = (const float*)d_in[12];
    const float* bfc1  = (const float*)d_in[13];
    const float* Wfc2  = (const float*)d_in[14];
    const float* bfc2  = (const float*)d_in[15];
    const float* bn2_g = (const float*)d_in[16];
    const float* bn2_b = (const float*)d_in[17];
    const float* bn2_m = (const float*)d_in[18];
    const float* bn2_v = (const float*)d_in[19];
    const float* alpha2= (const float*)d_in[20];
    float* out = (float*)d_out;

    char* ws = (char*)d_ws;
    bf16_t* t_b2    = (bf16_t*)(ws);
    bf16_t* WqkvT   = (bf16_t*)(ws + 16777216);
    bf16_t* WprojT  = (bf16_t*)(ws + 17170432);
    bf16_t* Wfc1T   = (bf16_t*)(ws + 17301504);
    bf16_t* Wfc2T   = (bf16_t*)(ws + 18350080);
    float*  ctxp    = (float*)(ws + 19398656);
    float*  ctx     = (float*)(ws + 21495808);
    bf16_t* t_b     = (bf16_t*)(ws + 21757952);
    bf16_t* qkv_b   = (bf16_t*)(ws + 38535168);
    bf16_t* img_b   = (bf16_t*)(ws + 88866816);
    bf16_t* conv_b  = (bf16_t*)(ws + 105644032);
    bf16_t* convT_b = (bf16_t*)(ws + 122421248);

    // ph1: merged prep (transpose x + all 4 weight casts)
    prep<<<9472, dim3(32, 8), 0, stream>>>(x, t_b, Wqkv, WqkvT, Wproj, WprojT,
                                           Wfc1, Wfc1T, Wfc2, Wfc2T);

    // ph2: qkv_b = bf16(t @ Wqkv + bqkv)
    gemm_swp<4><<<dim3(768 / 128, M_ / 128), 256, 0, stream>>>(
        WqkvT, t_b, bqkv, qkv_b, M_, 768, C_,
        nullptr, nullptr, nullptr, nullptr, nullptr, nullptr);

    // ph3: ctx = relu(k)^T v
    ctx_partial<<<dim3(8, B_ * NH_), 256, 0, stream>>>(qkv_b, ctxp);
    ctx_reduce<<<256, 256, 0, stream>>>(ctxp, ctx);

    // ph4: img_b = (relu(q)*scale) @ ctx   [B,C,N] bf16
    attn_out<<<dim3(N_ / 64, B_ * NH_), 256, 0, stream>>>(qkv_b, ctx, img_b);

    // ph5: depthwise conv (bf16 -> bf16)
    dwconv3x3<<<B_ * C_, 256, 0, stream>>>(img_b, dw_w, dw_b, conv_b);

    // ph6: conv_b -> convT_b (bf16 [B,N,C])
    transpose_b<<<dim3(N_ / 32, C_ / 32, B_), dim3(32, 8), 0, stream>>>(conv_b, convT_b);

    // ph7: t_b2 = repbn1(t_b + convT @ Wproj + bproj)
    gemm_swp<1><<<dim3(C_ / 128, M_ / 128), 256, 0, stream>>>(
        WprojT, convT_b, bproj, t_b2, M_, C_, C_,
        t_b, bn1_g, bn1_b, bn1_m, bn1_v, alpha1);

    // ph8: fused FFN v4 (1 barrier/chunk, dbuf hidden, covered W loads)
    ffn_fused<<<M_ / 64, 512, 0, stream>>>(
        t_b2, Wfc1T, Wfc2T, bfc1, bfc2,
        bn2_g, bn2_b, bn2_m, bn2_v, alpha2, out);
}